// Round 3
// baseline (3335.377 us; speedup 1.0000x reference)
//
#include <hip/hip_runtime.h>
#include <math.h>

typedef __attribute__((ext_vector_type(8))) short short8v;
typedef __attribute__((ext_vector_type(4))) float float4v;
typedef __attribute__((ext_vector_type(4))) unsigned short ushort4v;
typedef __attribute__((ext_vector_type(8))) unsigned short ushort8v;

#define CH 4096     // edges per binning block
#define MAXNB 800   // max buckets (100096/128 = 782)

__device__ inline unsigned short f2bf(float f) {
    unsigned u = __float_as_uint(f);
    return (unsigned short)((u + 0x7FFFu + ((u >> 16) & 1u)) >> 16);
}

// ---------------- binning pass 1: per-block bucket histogram -> global counts ----------------

__global__ __launch_bounds__(256) void bin1_kernel(const int* __restrict__ dst, int E, int NB,
                                                   int* __restrict__ gcnt,
                                                   int* __restrict__ blockBase) {
    __shared__ int h[MAXNB];
    int t = threadIdx.x;
    for (int i = t; i < NB; i += 256) h[i] = 0;
    __syncthreads();
    int e0 = blockIdx.x * CH;
#pragma unroll
    for (int i = 0; i < CH / 256; ++i) {
        int e = e0 + t + i * 256;
        if (e < E) atomicAdd(&h[dst[e] >> 7], 1);
    }
    __syncthreads();
    for (int b = t; b < NB; b += 256) {
        int c = h[b];
        int old = atomicAdd(&gcnt[b], c);
        blockBase[(size_t)blockIdx.x * MAXNB + b] = old;
    }
}

// ---------------- exclusive scan (single block, N <= 1024) ----------------

__global__ void scan1_kernel(const int* __restrict__ cnt, int N,
                             int* __restrict__ offs, int* __restrict__ partials) {
    __shared__ int sd[256];
    int t = threadIdx.x;
    int base = t * 4;
    int v[4]; int s = 0;
#pragma unroll
    for (int i = 0; i < 4; ++i) { v[i] = (base + i < N) ? cnt[base + i] : 0; s += v[i]; }
    sd[t] = s; __syncthreads();
    for (int d = 1; d < 256; d <<= 1) {
        int x = (t >= d) ? sd[t - d] : 0;
        __syncthreads();
        sd[t] += x;
        __syncthreads();
    }
    int p = sd[t] - s;
#pragma unroll
    for (int i = 0; i < 4; ++i) { if (base + i < N) offs[base + i] = p; p += v[i]; }
    if (t == 255) partials[0] = sd[255];
}

// ---------------- binning pass 2: block-local counting sort, coalesced flush ----------------

__global__ __launch_bounds__(256) void bin2_kernel(const int* __restrict__ src,
                                                   const int* __restrict__ dst, int E, int NB,
                                                   const int* __restrict__ boff,
                                                   const int* __restrict__ blockBase,
                                                   int2* __restrict__ ebuf) {
    __shared__ int h[MAXNB];
    __shared__ int intra[MAXNB];
    __shared__ int cursor[MAXNB];
    __shared__ int gbase[MAXNB];
    __shared__ int ps[256];
    __shared__ int2 sorted[CH];
    int t = threadIdx.x;
    int blk = blockIdx.x;
    for (int i = t; i < NB; i += 256) h[i] = 0;
    __syncthreads();
    int e0 = blk * CH;
#pragma unroll
    for (int i = 0; i < CH / 256; ++i) {
        int e = e0 + t + i * 256;
        if (e < E) atomicAdd(&h[dst[e] >> 7], 1);
    }
    __syncthreads();
    // block-wide exclusive scan of h[0..NB) -> intra
    int base4 = t * 4;
    int v[4]; int s = 0;
#pragma unroll
    for (int k = 0; k < 4; ++k) { v[k] = (base4 + k < NB) ? h[base4 + k] : 0; s += v[k]; }
    ps[t] = s; __syncthreads();
    for (int d = 1; d < 256; d <<= 1) {
        int x = (t >= d) ? ps[t - d] : 0;
        __syncthreads();
        ps[t] += x;
        __syncthreads();
    }
    int p = ps[t] - s;
#pragma unroll
    for (int k = 0; k < 4; ++k) { if (base4 + k < NB) intra[base4 + k] = p; p += v[k]; }
    __syncthreads();
    for (int b = t; b < NB; b += 256) {
        cursor[b] = intra[b];
        gbase[b] = boff[b] + blockBase[(size_t)blk * MAXNB + b] - intra[b];
    }
    __syncthreads();
#pragma unroll
    for (int i = 0; i < CH / 256; ++i) {
        int e = e0 + t + i * 256;
        if (e < E) {
            int d = dst[e];
            int b = d >> 7;
            int pos = atomicAdd(&cursor[b], 1);
            sorted[pos] = make_int2(src[e], d);
        }
    }
    __syncthreads();
    int lim = E - e0; if (lim > CH) lim = CH;
    for (int i = t; i < lim; i += 256) {
        int2 pr = sorted[i];
        int b = pr.y >> 7;
        ebuf[(size_t)gbase[b] + i] = pr;
    }
}

// ---------------- per-bucket degree -> dinv ----------------

__global__ __launch_bounds__(256) void degdinv_kernel(const int2* __restrict__ ebuf,
                                                      const int* __restrict__ boff,
                                                      const int* __restrict__ gcnt,
                                                      float* __restrict__ dinv, int N) {
    __shared__ int h[128];
    int t = threadIdx.x, b = blockIdx.x;
    if (t < 128) h[t] = 0;
    __syncthreads();
    int o = boff[b], c = gcnt[b];
    for (int i = t; i < c; i += 256) atomicAdd(&h[ebuf[o + i].y & 127], 1);
    __syncthreads();
    if (t < 128) {
        int vtx = b * 128 + t;
        if (vtx < N) dinv[vtx] = rsqrtf((float)(h[t] + 1));
    }
}

// ---------------- W split: W[K,128] fp32 -> WThi/WTlo[128][K] bf16 ----------------

__global__ void wsplit_kernel(const float* __restrict__ W, int K,
                              unsigned short* __restrict__ WThi,
                              unsigned short* __restrict__ WTlo) {
    int i = blockIdx.x * blockDim.x + threadIdx.x;
    if (i >= K * 128) return;
    int k = i >> 7, c = i & 127;
    float w = W[i];
    unsigned short hh = f2bf(w);
    float hf = __uint_as_float((unsigned)hh << 16);
    WThi[(size_t)c * K + k] = hh;
    WTlo[(size_t)c * K + k] = f2bf(w - hf);
}

// ---------------- split-bf16 MFMA GEMM: C[M,128] = A[M,K] @ W[K,128] ----------------

__global__ __launch_bounds__(256) void gemm_mfma_kernel(const float* __restrict__ A,
                                                        const unsigned short* __restrict__ WThi,
                                                        const unsigned short* __restrict__ WTlo,
                                                        float* __restrict__ C, int M, int K) {
    __shared__ unsigned short Ah[128 * 32];
    __shared__ unsigned short Al[128 * 32];
    __shared__ unsigned short Bh[128 * 32];
    __shared__ unsigned short Bl[128 * 32];
    int t = threadIdx.x;
    int w = t >> 6, l = t & 63;
    int lr = l & 15, lk = l >> 4;
    int row0 = blockIdx.x * 128;

    float4v acc[2][8];
#pragma unroll
    for (int mf = 0; mf < 2; ++mf)
#pragma unroll
        for (int nf = 0; nf < 8; ++nf) acc[mf][nf] = (float4v){0.f, 0.f, 0.f, 0.f};

    for (int k0 = 0; k0 < K; k0 += 32) {
#pragma unroll
        for (int i = 0; i < 4; ++i) {
            int idx = t + i * 256;
            int r = idx >> 3, c4 = (idx & 7) * 4;
            int gr = row0 + r;
            float4 v = {0.f, 0.f, 0.f, 0.f};
            if (gr < M) v = *(const float4*)(A + (size_t)gr * K + k0 + c4);
            float fs[4] = {v.x, v.y, v.z, v.w};
            ushort4v hi, lo;
#pragma unroll
            for (int j = 0; j < 4; ++j) {
                unsigned short hh = f2bf(fs[j]);
                float hf = __uint_as_float((unsigned)hh << 16);
                hi[j] = hh;
                lo[j] = f2bf(fs[j] - hf);
            }
            *(ushort4v*)&Ah[r * 32 + c4] = hi;
            *(ushort4v*)&Al[r * 32 + c4] = lo;
        }
#pragma unroll
        for (int i = 0; i < 2; ++i) {
            int cidx = t + i * 256;
            int col = cidx >> 2, q = cidx & 3;
            ushort8v vh = *(const ushort8v*)(WThi + (size_t)col * K + k0 + q * 8);
            ushort8v vl = *(const ushort8v*)(WTlo + (size_t)col * K + k0 + q * 8);
            *(ushort8v*)&Bh[col * 32 + q * 8] = vh;
            *(ushort8v*)&Bl[col * 32 + q * 8] = vl;
        }
        __syncthreads();

        short8v ah0 = *(const short8v*)&Ah[(w * 32 + lr) * 32 + lk * 8];
        short8v al0 = *(const short8v*)&Al[(w * 32 + lr) * 32 + lk * 8];
        short8v ah1 = *(const short8v*)&Ah[(w * 32 + 16 + lr) * 32 + lk * 8];
        short8v al1 = *(const short8v*)&Al[(w * 32 + 16 + lr) * 32 + lk * 8];
#pragma unroll
        for (int nf = 0; nf < 8; ++nf) {
            short8v bh = *(const short8v*)&Bh[(nf * 16 + lr) * 32 + lk * 8];
            short8v bl = *(const short8v*)&Bl[(nf * 16 + lr) * 32 + lk * 8];
            acc[0][nf] = __builtin_amdgcn_mfma_f32_16x16x32_bf16(ah0, bh, acc[0][nf], 0, 0, 0);
            acc[0][nf] = __builtin_amdgcn_mfma_f32_16x16x32_bf16(ah0, bl, acc[0][nf], 0, 0, 0);
            acc[0][nf] = __builtin_amdgcn_mfma_f32_16x16x32_bf16(al0, bh, acc[0][nf], 0, 0, 0);
            acc[1][nf] = __builtin_amdgcn_mfma_f32_16x16x32_bf16(ah1, bh, acc[1][nf], 0, 0, 0);
            acc[1][nf] = __builtin_amdgcn_mfma_f32_16x16x32_bf16(ah1, bl, acc[1][nf], 0, 0, 0);
            acc[1][nf] = __builtin_amdgcn_mfma_f32_16x16x32_bf16(al1, bh, acc[1][nf], 0, 0, 0);
        }
        __syncthreads();
    }
#pragma unroll
    for (int mf = 0; mf < 2; ++mf)
#pragma unroll
        for (int nf = 0; nf < 8; ++nf)
#pragma unroll
            for (int r = 0; r < 4; ++r) {
                int grow = row0 + w * 32 + mf * 16 + lk * 4 + r;
                if (grow < M) C[(size_t)grow * 128 + nf * 16 + lr] = acc[mf][nf][r];
            }
}

// ---------------- bucket aggregation: one block per bucket, 128x128 LDS tile ----------------
// out[v] = sum_{e:dst=v} dinv[src]*dinv[v]*xw[src] + dinv[v]^2*xw[v] + bias, then ELU

__global__ __launch_bounds__(256) void agg_bucket_kernel(const float* __restrict__ xw,
                                                         const int2* __restrict__ ebuf,
                                                         const int* __restrict__ boff,
                                                         const int* __restrict__ gcnt,
                                                         const float* __restrict__ dinv,
                                                         const float* __restrict__ bias,
                                                         float* __restrict__ out, int N) {
    __shared__ float tile[128 * 128];   // 64KB
    int t = threadIdx.x, b = blockIdx.x;
    int v0 = b * 128;
    for (int i = t; i < 128 * 128; i += 256) tile[i] = 0.f;
    __syncthreads();
    int o = boff[b], c = gcnt[b];
    int w = t >> 6, lane = t & 63;

    for (int base = w * 64; base < c; base += 256) {
        int rem = c - base; if (rem > 64) rem = 64;
        int li = base + lane;
        int2 pr = (li < c) ? ebuf[o + li] : make_int2(0, v0);
        float nl = (li < c) ? dinv[pr.x] * dinv[pr.y] : 0.f;
        int rl = pr.y & 127;
        int j = 0;
        for (; j + 4 <= rem; j += 4) {
            int s0 = __shfl(pr.x, j), s1 = __shfl(pr.x, j + 1);
            int s2 = __shfl(pr.x, j + 2), s3 = __shfl(pr.x, j + 3);
            float n0 = __shfl(nl, j), n1 = __shfl(nl, j + 1);
            float n2 = __shfl(nl, j + 2), n3 = __shfl(nl, j + 3);
            int r0 = __shfl(rl, j), r1 = __shfl(rl, j + 1);
            int r2 = __shfl(rl, j + 2), r3 = __shfl(rl, j + 3);
            float x0 = xw[(size_t)s0 * 128 + lane],      y0 = xw[(size_t)s0 * 128 + 64 + lane];
            float x1 = xw[(size_t)s1 * 128 + lane],      y1 = xw[(size_t)s1 * 128 + 64 + lane];
            float x2 = xw[(size_t)s2 * 128 + lane],      y2 = xw[(size_t)s2 * 128 + 64 + lane];
            float x3 = xw[(size_t)s3 * 128 + lane],      y3 = xw[(size_t)s3 * 128 + 64 + lane];
            atomicAdd(&tile[r0 * 128 + lane], n0 * x0);
            atomicAdd(&tile[r0 * 128 + 64 + lane], n0 * y0);
            atomicAdd(&tile[r1 * 128 + lane], n1 * x1);
            atomicAdd(&tile[r1 * 128 + 64 + lane], n1 * y1);
            atomicAdd(&tile[r2 * 128 + lane], n2 * x2);
            atomicAdd(&tile[r2 * 128 + 64 + lane], n2 * y2);
            atomicAdd(&tile[r3 * 128 + lane], n3 * x3);
            atomicAdd(&tile[r3 * 128 + 64 + lane], n3 * y3);
        }
        for (; j < rem; ++j) {
            int s = __shfl(pr.x, j);
            float n = __shfl(nl, j);
            int r = __shfl(rl, j);
            float x = xw[(size_t)s * 128 + lane], y = xw[(size_t)s * 128 + 64 + lane];
            atomicAdd(&tile[r * 128 + lane], n * x);
            atomicAdd(&tile[r * 128 + 64 + lane], n * y);
        }
    }
    __syncthreads();
    // epilogue: self-loop + bias + ELU, coalesced write
    for (int i = t; i < 128 * 128; i += 256) {
        int r = i >> 7, ccol = i & 127;
        int vtx = v0 + r;
        if (vtx < N) {
            float dv = dinv[vtx];
            float val = tile[i] + dv * dv * xw[(size_t)vtx * 128 + ccol] + bias[ccol];
            val = val > 0.f ? val : expm1f(val);
            out[(size_t)vtx * 128 + ccol] = val;
        }
    }
}

// ---------------- root aggregation: one wave per root, scan its bucket ----------------

__global__ __launch_bounds__(256) void root_agg_kernel(const float* __restrict__ xw,
                                                       const int2* __restrict__ ebuf,
                                                       const int* __restrict__ boff,
                                                       const int* __restrict__ gcnt,
                                                       const float* __restrict__ dinv,
                                                       const float* __restrict__ bias,
                                                       const int* __restrict__ roots, int R,
                                                       float* __restrict__ feat, int stride,
                                                       int col0) {
    int wid = (blockIdx.x * blockDim.x + threadIdx.x) >> 6;
    if (wid >= R) return;
    int lane = threadIdx.x & 63;
    int r = roots[wid];
    int b = r >> 7;
    int o = boff[b], c = gcnt[b];
    float dv = dinv[r];
    float ax = 0.f, ay = 0.f;
    for (int base = 0; base < c; base += 64) {
        int li = base + lane;
        int2 pr = (li < c) ? ebuf[o + li] : make_int2(0, -1);
        unsigned long long mask = __ballot(pr.y == r);
        while (mask) {
            int j = __ffsll(mask) - 1;
            mask &= mask - 1;
            int s = __shfl(pr.x, j);
            float nrm = dv * dinv[s];
            ax += nrm * xw[(size_t)s * 128 + lane];
            ay += nrm * xw[(size_t)s * 128 + 64 + lane];
        }
    }
    ax += dv * dv * xw[(size_t)r * 128 + lane];
    ay += dv * dv * xw[(size_t)r * 128 + 64 + lane];
    ax += bias[lane];
    ay += bias[64 + lane];
    ax = ax > 0.f ? ax : expm1f(ax);
    ay = ay > 0.f ? ay : expm1f(ay);
    feat[(size_t)wid * stride + col0 + lane] = ax;
    feat[(size_t)wid * stride + col0 + 64 + lane] = ay;
}

// ---------------- head: logits + log_softmax over 2048 roots ----------------

__global__ __launch_bounds__(256) void head_kernel(const float* __restrict__ feat,
                                                   const float* __restrict__ fcw,
                                                   const float* __restrict__ fcb,
                                                   float* __restrict__ out, int R) {
    int wid = (blockIdx.x * blockDim.x + threadIdx.x) >> 6;
    if (wid >= R) return;
    int lane = threadIdx.x & 63;
    const float* fr = feat + (size_t)wid * 256;
    float a0 = 0.f, a1 = 0.f, a2 = 0.f, a3 = 0.f;
    for (int k = lane; k < 256; k += 64) {
        float f = fr[k];
        float4 w = *(const float4*)(fcw + k * 4);
        a0 += f * w.x; a1 += f * w.y; a2 += f * w.z; a3 += f * w.w;
    }
#pragma unroll
    for (int d = 1; d < 64; d <<= 1) {
        a0 += __shfl_xor(a0, d); a1 += __shfl_xor(a1, d);
        a2 += __shfl_xor(a2, d); a3 += __shfl_xor(a3, d);
    }
    if (lane == 0) {
        a0 += fcb[0]; a1 += fcb[1]; a2 += fcb[2]; a3 += fcb[3];
        float m = fmaxf(fmaxf(a0, a1), fmaxf(a2, a3));
        float s = expf(a0 - m) + expf(a1 - m) + expf(a2 - m) + expf(a3 - m);
        float ls = logf(s) + m;
        float4 rr = {a0 - ls, a1 - ls, a2 - ls, a3 - ls};
        *(float4*)(out + (size_t)wid * 4) = rr;
    }
}

// ---------------- launch ----------------

extern "C" void kernel_launch(void* const* d_in, const int* in_sizes, int n_in,
                              void* d_out, int out_size, void* d_ws, size_t ws_size,
                              hipStream_t stream) {
    const float* x    = (const float*)d_in[0];
    const int*   ei   = (const int*)d_in[1];
    const int*   bei  = (const int*)d_in[2];
    const int*   roots= (const int*)d_in[3];
    const float* w1 = (const float*)d_in[4];
    const float* b1 = (const float*)d_in[5];
    const float* w2 = (const float*)d_in[6];
    const float* b2 = (const float*)d_in[7];
    const float* w3 = (const float*)d_in[8];
    const float* b3 = (const float*)d_in[9];
    const float* w4 = (const float*)d_in[10];
    const float* b4 = (const float*)d_in[11];
    const float* fcw = (const float*)d_in[12];
    const float* fcb = (const float*)d_in[13];
    float* out = (float*)d_out;

    const int N = in_sizes[0] / 256;
    const int E = in_sizes[1] / 2;
    const int R = in_sizes[3];
    const int NB = (N + 127) >> 7;
    const int nblk = (E + CH - 1) / CH;

    char* ws = (char*)d_ws;
    size_t off = 0;
    auto alloc = [&](size_t b) { size_t o = off; off += (b + 255) & ~(size_t)255; return o; };
    float* xw   = (float*)(ws + alloc((size_t)N * 128 * 4));
    float* h    = (float*)(ws + alloc((size_t)N * 128 * 4));
    int2*  ebuf = (int2*)(ws + alloc((size_t)E * 8));
    int*   blockBase = (int*)(ws + alloc((size_t)nblk * MAXNB * 4));
    int*   gcnt = (int*)(ws + alloc((size_t)MAXNB * 4));
    int*   boff = (int*)(ws + alloc((size_t)MAXNB * 4));
    float* dinv = (float*)(ws + alloc((size_t)N * 4));
    float* feat = (float*)(ws + alloc((size_t)R * 256 * 4));
    int*   partials = (int*)(ws + alloc(1024));
    unsigned short* WThi = (unsigned short*)(ws + alloc((size_t)128 * 256 * 2));
    unsigned short* WTlo = (unsigned short*)(ws + alloc((size_t)128 * 256 * 2));

    for (int br = 0; br < 2; ++br) {
        const int* e    = (br == 0) ? ei : bei;
        const int* srcp = e;
        const int* dstp = e + E;
        const float* wA = (br == 0) ? w1 : w3;
        const float* bA = (br == 0) ? b1 : b3;
        const float* wB = (br == 0) ? w2 : w4;
        const float* bB = (br == 0) ? b2 : b4;

        hipMemsetAsync(gcnt, 0, (size_t)MAXNB * 4, stream);
        bin1_kernel<<<nblk, 256, 0, stream>>>(dstp, E, NB, gcnt, blockBase);
        scan1_kernel<<<1, 256, 0, stream>>>(gcnt, NB, boff, partials);
        bin2_kernel<<<nblk, 256, 0, stream>>>(srcp, dstp, E, NB, boff, blockBase, ebuf);
        degdinv_kernel<<<NB, 256, 0, stream>>>(ebuf, boff, gcnt, dinv, N);

        // layer 1
        wsplit_kernel<<<(256 * 128 + 255) / 256, 256, 0, stream>>>(wA, 256, WThi, WTlo);
        gemm_mfma_kernel<<<(N + 127) / 128, 256, 0, stream>>>(x, WThi, WTlo, xw, N, 256);
        agg_bucket_kernel<<<NB, 256, 0, stream>>>(xw, ebuf, boff, gcnt, dinv, bA, h, N);
        // layer 2 (aggregate only at roots)
        wsplit_kernel<<<(128 * 128 + 255) / 256, 256, 0, stream>>>(wB, 128, WThi, WTlo);
        gemm_mfma_kernel<<<(N + 127) / 128, 256, 0, stream>>>(h, WThi, WTlo, xw, N, 128);
        root_agg_kernel<<<((size_t)R * 64 + 255) / 256, 256, 0, stream>>>(
            xw, ebuf, boff, gcnt, dinv, bB, roots, R, feat, 256, br * 128);
    }
    head_kernel<<<((size_t)R * 64 + 255) / 256, 256, 0, stream>>>(feat, fcw, fcb, out, R);
}

// Round 4
// 718.767 us; speedup vs baseline: 4.6404x; 4.6404x over previous
//
#include <hip/hip_runtime.h>
#include <math.h>

typedef __attribute__((ext_vector_type(8))) short short8v;
typedef __attribute__((ext_vector_type(4))) float float4v;
typedef __attribute__((ext_vector_type(4))) unsigned short ushort4v;
typedef __attribute__((ext_vector_type(8))) unsigned short ushort8v;

#define CH 4096     // edges per binning block
#define MAXNB 800   // max buckets (100096/128 = 782)

__device__ inline unsigned short f2bf(float f) {
    unsigned u = __float_as_uint(f);
    return (unsigned short)((u + 0x7FFFu + ((u >> 16) & 1u)) >> 16);
}

// ---------------- binning pass 1: per-block bucket histogram -> global counts ----------------

__global__ __launch_bounds__(256) void bin1_kernel(const int* __restrict__ dst, int E, int NB,
                                                   int* __restrict__ gcnt,
                                                   int* __restrict__ blockBase) {
    __shared__ int h[MAXNB];
    int t = threadIdx.x;
    for (int i = t; i < NB; i += 256) h[i] = 0;
    __syncthreads();
    int e0 = blockIdx.x * CH;
#pragma unroll
    for (int i = 0; i < CH / 256; ++i) {
        int e = e0 + t + i * 256;
        if (e < E) atomicAdd(&h[dst[e] >> 7], 1);
    }
    __syncthreads();
    for (int b = t; b < NB; b += 256) {
        int c = h[b];
        int old = atomicAdd(&gcnt[b], c);
        blockBase[(size_t)blockIdx.x * MAXNB + b] = old;
    }
}

// ---------------- exclusive scan (single block, N <= 1024) ----------------

__global__ void scan1_kernel(const int* __restrict__ cnt, int N,
                             int* __restrict__ offs) {
    __shared__ int sd[256];
    int t = threadIdx.x;
    int base = t * 4;
    int v[4]; int s = 0;
#pragma unroll
    for (int i = 0; i < 4; ++i) { v[i] = (base + i < N) ? cnt[base + i] : 0; s += v[i]; }
    sd[t] = s; __syncthreads();
    for (int d = 1; d < 256; d <<= 1) {
        int x = (t >= d) ? sd[t - d] : 0;
        __syncthreads();
        sd[t] += x;
        __syncthreads();
    }
    int p = sd[t] - s;
#pragma unroll
    for (int i = 0; i < 4; ++i) { if (base + i < N) offs[base + i] = p; p += v[i]; }
}

// ---------------- binning pass 2: block-local counting sort, coalesced flush ----------------

__global__ __launch_bounds__(256) void bin2_kernel(const int* __restrict__ src,
                                                   const int* __restrict__ dst, int E, int NB,
                                                   const int* __restrict__ boff,
                                                   const int* __restrict__ blockBase,
                                                   int2* __restrict__ ebuf) {
    __shared__ int h[MAXNB];
    __shared__ int intra[MAXNB];
    __shared__ int cursor[MAXNB];
    __shared__ int gbase[MAXNB];
    __shared__ int ps[256];
    __shared__ int2 sorted[CH];
    int t = threadIdx.x;
    int blk = blockIdx.x;
    for (int i = t; i < NB; i += 256) h[i] = 0;
    __syncthreads();
    int e0 = blk * CH;
#pragma unroll
    for (int i = 0; i < CH / 256; ++i) {
        int e = e0 + t + i * 256;
        if (e < E) atomicAdd(&h[dst[e] >> 7], 1);
    }
    __syncthreads();
    // block-wide exclusive scan of h[0..NB) -> intra
    int base4 = t * 4;
    int v[4]; int s = 0;
#pragma unroll
    for (int k = 0; k < 4; ++k) { v[k] = (base4 + k < NB) ? h[base4 + k] : 0; s += v[k]; }
    ps[t] = s; __syncthreads();
    for (int d = 1; d < 256; d <<= 1) {
        int x = (t >= d) ? ps[t - d] : 0;
        __syncthreads();
        ps[t] += x;
        __syncthreads();
    }
    int p = ps[t] - s;
#pragma unroll
    for (int k = 0; k < 4; ++k) { if (base4 + k < NB) intra[base4 + k] = p; p += v[k]; }
    __syncthreads();
    for (int b = t; b < NB; b += 256) {
        cursor[b] = intra[b];
        gbase[b] = boff[b] + blockBase[(size_t)blk * MAXNB + b] - intra[b];
    }
    __syncthreads();
#pragma unroll
    for (int i = 0; i < CH / 256; ++i) {
        int e = e0 + t + i * 256;
        if (e < E) {
            int d = dst[e];
            int b = d >> 7;
            int pos = atomicAdd(&cursor[b], 1);
            sorted[pos] = make_int2(src[e], d);
        }
    }
    __syncthreads();
    int lim = E - e0; if (lim > CH) lim = CH;
    for (int i = t; i < lim; i += 256) {
        int2 pr = sorted[i];
        int b = pr.y >> 7;
        ebuf[(size_t)gbase[b] + i] = pr;
    }
}

// ---------------- per-bucket CSR build: node histogram -> scan -> scatter ----------------
// also emits offs/cnt/dinv per node (replaces count_dst + N-length scans)

__global__ __launch_bounds__(256) void csr_build_kernel(const int2* __restrict__ ebuf,
                                                        const int* __restrict__ boff,
                                                        const int* __restrict__ gcnt,
                                                        int* __restrict__ csr,
                                                        int* __restrict__ offs,
                                                        int* __restrict__ cnt,
                                                        float* __restrict__ dinv, int N) {
    __shared__ int h[128];
    __shared__ int sc[128];
    __shared__ int loc[128];
    __shared__ int cur[128];
    int t = threadIdx.x, b = blockIdx.x;
    if (t < 128) h[t] = 0;
    __syncthreads();
    int o = boff[b], c = gcnt[b];
    for (int i = t; i < c; i += 256) atomicAdd(&h[ebuf[o + i].y & 127], 1);
    __syncthreads();
    if (t < 128) sc[t] = h[t];
    __syncthreads();
    for (int d = 1; d < 128; d <<= 1) {
        int x = (t >= d && t < 128) ? sc[t - d] : 0;
        __syncthreads();
        if (t < 128) sc[t] += x;
        __syncthreads();
    }
    if (t < 128) { loc[t] = sc[t] - h[t]; cur[t] = loc[t]; }
    __syncthreads();
    for (int i = t; i < c; i += 256) {
        int2 pr = ebuf[o + i];
        int pos = atomicAdd(&cur[pr.y & 127], 1);
        csr[o + pos] = pr.x;                       // random only within 8KB region -> L2
    }
    if (t < 128) {
        int v = b * 128 + t;
        if (v < N) {
            offs[v] = o + loc[t];
            cnt[v] = h[t];
            dinv[v] = rsqrtf((float)(h[t] + 1));
        }
    }
}

// ---------------- W split: W[K,128] fp32 -> WThi/WTlo[128][K] bf16 ----------------

__global__ void wsplit_kernel(const float* __restrict__ W, int K,
                              unsigned short* __restrict__ WThi,
                              unsigned short* __restrict__ WTlo) {
    int i = blockIdx.x * blockDim.x + threadIdx.x;
    if (i >= K * 128) return;
    int k = i >> 7, c = i & 127;
    float w = W[i];
    unsigned short hh = f2bf(w);
    float hf = __uint_as_float((unsigned)hh << 16);
    WThi[(size_t)c * K + k] = hh;
    WTlo[(size_t)c * K + k] = f2bf(w - hf);
}

// ---------------- split-bf16 MFMA GEMM: C[M,128] = A[M,K] @ W[K,128] ----------------

__global__ __launch_bounds__(256) void gemm_mfma_kernel(const float* __restrict__ A,
                                                        const unsigned short* __restrict__ WThi,
                                                        const unsigned short* __restrict__ WTlo,
                                                        float* __restrict__ C, int M, int K) {
    __shared__ unsigned short Ah[128 * 32];
    __shared__ unsigned short Al[128 * 32];
    __shared__ unsigned short Bh[128 * 32];
    __shared__ unsigned short Bl[128 * 32];
    int t = threadIdx.x;
    int w = t >> 6, l = t & 63;
    int lr = l & 15, lk = l >> 4;
    int row0 = blockIdx.x * 128;

    float4v acc[2][8];
#pragma unroll
    for (int mf = 0; mf < 2; ++mf)
#pragma unroll
        for (int nf = 0; nf < 8; ++nf) acc[mf][nf] = (float4v){0.f, 0.f, 0.f, 0.f};

    for (int k0 = 0; k0 < K; k0 += 32) {
#pragma unroll
        for (int i = 0; i < 4; ++i) {
            int idx = t + i * 256;
            int r = idx >> 3, c4 = (idx & 7) * 4;
            int gr = row0 + r;
            float4 v = {0.f, 0.f, 0.f, 0.f};
            if (gr < M) v = *(const float4*)(A + (size_t)gr * K + k0 + c4);
            float fs[4] = {v.x, v.y, v.z, v.w};
            ushort4v hi, lo;
#pragma unroll
            for (int j = 0; j < 4; ++j) {
                unsigned short hh = f2bf(fs[j]);
                float hf = __uint_as_float((unsigned)hh << 16);
                hi[j] = hh;
                lo[j] = f2bf(fs[j] - hf);
            }
            *(ushort4v*)&Ah[r * 32 + c4] = hi;
            *(ushort4v*)&Al[r * 32 + c4] = lo;
        }
#pragma unroll
        for (int i = 0; i < 2; ++i) {
            int cidx = t + i * 256;
            int col = cidx >> 2, q = cidx & 3;
            ushort8v vh = *(const ushort8v*)(WThi + (size_t)col * K + k0 + q * 8);
            ushort8v vl = *(const ushort8v*)(WTlo + (size_t)col * K + k0 + q * 8);
            *(ushort8v*)&Bh[col * 32 + q * 8] = vh;
            *(ushort8v*)&Bl[col * 32 + q * 8] = vl;
        }
        __syncthreads();

        short8v ah0 = *(const short8v*)&Ah[(w * 32 + lr) * 32 + lk * 8];
        short8v al0 = *(const short8v*)&Al[(w * 32 + lr) * 32 + lk * 8];
        short8v ah1 = *(const short8v*)&Ah[(w * 32 + 16 + lr) * 32 + lk * 8];
        short8v al1 = *(const short8v*)&Al[(w * 32 + 16 + lr) * 32 + lk * 8];
#pragma unroll
        for (int nf = 0; nf < 8; ++nf) {
            short8v bh = *(const short8v*)&Bh[(nf * 16 + lr) * 32 + lk * 8];
            short8v bl = *(const short8v*)&Bl[(nf * 16 + lr) * 32 + lk * 8];
            acc[0][nf] = __builtin_amdgcn_mfma_f32_16x16x32_bf16(ah0, bh, acc[0][nf], 0, 0, 0);
            acc[0][nf] = __builtin_amdgcn_mfma_f32_16x16x32_bf16(ah0, bl, acc[0][nf], 0, 0, 0);
            acc[0][nf] = __builtin_amdgcn_mfma_f32_16x16x32_bf16(al0, bh, acc[0][nf], 0, 0, 0);
            acc[1][nf] = __builtin_amdgcn_mfma_f32_16x16x32_bf16(ah1, bh, acc[1][nf], 0, 0, 0);
            acc[1][nf] = __builtin_amdgcn_mfma_f32_16x16x32_bf16(ah1, bl, acc[1][nf], 0, 0, 0);
            acc[1][nf] = __builtin_amdgcn_mfma_f32_16x16x32_bf16(al1, bh, acc[1][nf], 0, 0, 0);
        }
        __syncthreads();
    }
#pragma unroll
    for (int mf = 0; mf < 2; ++mf)
#pragma unroll
        for (int nf = 0; nf < 8; ++nf)
#pragma unroll
            for (int r = 0; r < 4; ++r) {
                int grow = row0 + w * 32 + mf * 16 + lk * 4 + r;
                if (grow < M) C[(size_t)grow * 128 + nf * 16 + lr] = acc[mf][nf][r];
            }
}

// ---------------- aggregation: one wave per output row (CSR) ----------------

__global__ __launch_bounds__(256) void agg_kernel(const float* __restrict__ xw,
                                                  const int* __restrict__ csr,
                                                  const int* __restrict__ offs,
                                                  const int* __restrict__ cnt,
                                                  const float* __restrict__ dinv,
                                                  const float* __restrict__ bias,
                                                  const int* __restrict__ nodelist, int nwork,
                                                  float* __restrict__ out, int out_stride,
                                                  int out_col0) {
    int wid = (blockIdx.x * blockDim.x + threadIdx.x) >> 6;
    if (wid >= nwork) return;
    int lane = threadIdx.x & 63;
    int v = nodelist ? nodelist[wid] : wid;
    int o = offs[v];
    int c = cnt[v];
    float dv = dinv[v];
    float ax = 0.f, ay = 0.f;

    for (int base = 0; base < c; base += 64) {
        int rem = c - base; if (rem > 64) rem = 64;
        int li = base + lane; if (li >= c) li = c - 1;
        int s_l = csr[o + li];
        float d_l = dinv[s_l];
        int j = 0;
        for (; j + 4 <= rem; j += 4) {
            int s0 = __shfl(s_l, j);     int s1 = __shfl(s_l, j + 1);
            int s2 = __shfl(s_l, j + 2); int s3 = __shfl(s_l, j + 3);
            float e0 = __shfl(d_l, j);     float e1 = __shfl(d_l, j + 1);
            float e2 = __shfl(d_l, j + 2); float e3 = __shfl(d_l, j + 3);
            float2 v0 = *(const float2*)(xw + (size_t)s0 * 128 + lane * 2);
            float2 v1 = *(const float2*)(xw + (size_t)s1 * 128 + lane * 2);
            float2 v2 = *(const float2*)(xw + (size_t)s2 * 128 + lane * 2);
            float2 v3 = *(const float2*)(xw + (size_t)s3 * 128 + lane * 2);
            ax += e0 * v0.x + e1 * v1.x + e2 * v2.x + e3 * v3.x;
            ay += e0 * v0.y + e1 * v1.y + e2 * v2.y + e3 * v3.y;
        }
        for (; j < rem; ++j) {
            int s = __shfl(s_l, j);
            float e = __shfl(d_l, j);
            float2 vv = *(const float2*)(xw + (size_t)s * 128 + lane * 2);
            ax += e * vv.x; ay += e * vv.y;
        }
    }
    // self loop
    float2 sv = *(const float2*)(xw + (size_t)v * 128 + lane * 2);
    ax += dv * sv.x; ay += dv * sv.y;
    ax = dv * ax + bias[lane * 2];
    ay = dv * ay + bias[lane * 2 + 1];
    ax = ax > 0.f ? ax : expm1f(ax);
    ay = ay > 0.f ? ay : expm1f(ay);
    float2 res = {ax, ay};
    *(float2*)(out + (size_t)wid * out_stride + out_col0 + lane * 2) = res;
}

// ---------------- head: logits + log_softmax over 2048 roots ----------------

__global__ __launch_bounds__(256) void head_kernel(const float* __restrict__ feat,
                                                   const float* __restrict__ fcw,
                                                   const float* __restrict__ fcb,
                                                   float* __restrict__ out, int R) {
    int wid = (blockIdx.x * blockDim.x + threadIdx.x) >> 6;
    if (wid >= R) return;
    int lane = threadIdx.x & 63;
    const float* fr = feat + (size_t)wid * 256;
    float a0 = 0.f, a1 = 0.f, a2 = 0.f, a3 = 0.f;
    for (int k = lane; k < 256; k += 64) {
        float f = fr[k];
        float4 w = *(const float4*)(fcw + k * 4);
        a0 += f * w.x; a1 += f * w.y; a2 += f * w.z; a3 += f * w.w;
    }
#pragma unroll
    for (int d = 1; d < 64; d <<= 1) {
        a0 += __shfl_xor(a0, d); a1 += __shfl_xor(a1, d);
        a2 += __shfl_xor(a2, d); a3 += __shfl_xor(a3, d);
    }
    if (lane == 0) {
        a0 += fcb[0]; a1 += fcb[1]; a2 += fcb[2]; a3 += fcb[3];
        float m = fmaxf(fmaxf(a0, a1), fmaxf(a2, a3));
        float s = expf(a0 - m) + expf(a1 - m) + expf(a2 - m) + expf(a3 - m);
        float ls = logf(s) + m;
        float4 rr = {a0 - ls, a1 - ls, a2 - ls, a3 - ls};
        *(float4*)(out + (size_t)wid * 4) = rr;
    }
}

// ---------------- launch ----------------

extern "C" void kernel_launch(void* const* d_in, const int* in_sizes, int n_in,
                              void* d_out, int out_size, void* d_ws, size_t ws_size,
                              hipStream_t stream) {
    const float* x    = (const float*)d_in[0];
    const int*   ei   = (const int*)d_in[1];
    const int*   bei  = (const int*)d_in[2];
    const int*   roots= (const int*)d_in[3];
    const float* w1 = (const float*)d_in[4];
    const float* b1 = (const float*)d_in[5];
    const float* w2 = (const float*)d_in[6];
    const float* b2 = (const float*)d_in[7];
    const float* w3 = (const float*)d_in[8];
    const float* b3 = (const float*)d_in[9];
    const float* w4 = (const float*)d_in[10];
    const float* b4 = (const float*)d_in[11];
    const float* fcw = (const float*)d_in[12];
    const float* fcb = (const float*)d_in[13];
    float* out = (float*)d_out;

    const int N = in_sizes[0] / 256;
    const int E = in_sizes[1] / 2;
    const int R = in_sizes[3];
    const int NB = (N + 127) >> 7;
    const int nblk = (E + CH - 1) / CH;

    char* ws = (char*)d_ws;
    size_t off = 0;
    auto alloc = [&](size_t b) { size_t o = off; off += (b + 255) & ~(size_t)255; return o; };
    float* xw   = (float*)(ws + alloc((size_t)N * 128 * 4));
    float* h    = (float*)(ws + alloc((size_t)N * 128 * 4));
    int2*  ebuf = (int2*)(ws + alloc((size_t)E * 8));
    int*   csr  = (int*)(ws + alloc((size_t)E * 4));
    int*   blockBase = (int*)(ws + alloc((size_t)nblk * MAXNB * 4));
    int*   gcnt = (int*)(ws + alloc((size_t)MAXNB * 4));
    int*   boff = (int*)(ws + alloc((size_t)MAXNB * 4));
    int*   offs = (int*)(ws + alloc((size_t)N * 4));
    int*   cnt  = (int*)(ws + alloc((size_t)N * 4));
    float* dinv = (float*)(ws + alloc((size_t)N * 4));
    float* feat = (float*)(ws + alloc((size_t)R * 256 * 4));
    unsigned short* WThi = (unsigned short*)(ws + alloc((size_t)128 * 256 * 2));
    unsigned short* WTlo = (unsigned short*)(ws + alloc((size_t)128 * 256 * 2));

    for (int br = 0; br < 2; ++br) {
        const int* e    = (br == 0) ? ei : bei;
        const int* srcp = e;
        const int* dstp = e + E;
        const float* wA = (br == 0) ? w1 : w3;
        const float* bA = (br == 0) ? b1 : b3;
        const float* wB = (br == 0) ? w2 : w4;
        const float* bB = (br == 0) ? b2 : b4;

        hipMemsetAsync(gcnt, 0, (size_t)MAXNB * 4, stream);
        bin1_kernel<<<nblk, 256, 0, stream>>>(dstp, E, NB, gcnt, blockBase);
        scan1_kernel<<<1, 256, 0, stream>>>(gcnt, NB, boff);
        bin2_kernel<<<nblk, 256, 0, stream>>>(srcp, dstp, E, NB, boff, blockBase, ebuf);
        csr_build_kernel<<<NB, 256, 0, stream>>>(ebuf, boff, gcnt, csr, offs, cnt, dinv, N);

        // layer 1: full aggregation (h needed at all nodes for layer-2 GEMM)
        wsplit_kernel<<<(256 * 128 + 255) / 256, 256, 0, stream>>>(wA, 256, WThi, WTlo);
        gemm_mfma_kernel<<<(N + 127) / 128, 256, 0, stream>>>(x, WThi, WTlo, xw, N, 256);
        agg_kernel<<<((size_t)N * 64 + 255) / 256, 256, 0, stream>>>(
            xw, csr, offs, cnt, dinv, bA, nullptr, N, h, 128, 0);
        // layer 2: aggregation only at roots
        wsplit_kernel<<<(128 * 128 + 255) / 256, 256, 0, stream>>>(wB, 128, WThi, WTlo);
        gemm_mfma_kernel<<<(N + 127) / 128, 256, 0, stream>>>(h, WThi, WTlo, xw, N, 128);
        agg_kernel<<<((size_t)R * 64 + 255) / 256, 256, 0, stream>>>(
            xw, csr, offs, cnt, dinv, bB, roots, R, feat, 256, br * 128);
    }
    head_kernel<<<((size_t)R * 64 + 255) / 256, 256, 0, stream>>>(feat, fcw, fcb, out, R);
}

// Round 5
// 572.497 us; speedup vs baseline: 5.8260x; 1.2555x over previous
//
#include <hip/hip_runtime.h>
#include <hip/hip_fp16.h>
#include <math.h>

typedef __attribute__((ext_vector_type(8))) short short8v;
typedef __attribute__((ext_vector_type(4))) float float4v;
typedef __attribute__((ext_vector_type(4))) unsigned short ushort4v;
typedef __attribute__((ext_vector_type(8))) unsigned short ushort8v;

#define CH 4096     // edges per binning block
#define MAXNB 800   // max buckets (100096/128 = 782)

__device__ inline unsigned short f2bf(float f) {
    unsigned u = __float_as_uint(f);
    return (unsigned short)((u + 0x7FFFu + ((u >> 16) & 1u)) >> 16);
}

// ---------------- binning pass 1: per-block bucket histogram -> global counts ----------------

__global__ __launch_bounds__(256) void bin1_kernel(const int* __restrict__ dst, int E, int NB,
                                                   int* __restrict__ gcnt,
                                                   int* __restrict__ blockBase) {
    __shared__ int h[MAXNB];
    int t = threadIdx.x;
    for (int i = t; i < NB; i += 256) h[i] = 0;
    __syncthreads();
    int e0 = blockIdx.x * CH;
#pragma unroll
    for (int i = 0; i < CH / 256; ++i) {
        int e = e0 + t + i * 256;
        if (e < E) atomicAdd(&h[dst[e] >> 7], 1);
    }
    __syncthreads();
    for (int b = t; b < NB; b += 256) {
        int c = h[b];
        int old = atomicAdd(&gcnt[b], c);
        blockBase[(size_t)blockIdx.x * MAXNB + b] = old;
    }
}

// ---------------- exclusive scan (single block, NB <= 1024) ----------------

__global__ void scan1_kernel(const int* __restrict__ cnt, int N,
                             int* __restrict__ offs) {
    __shared__ int sd[256];
    int t = threadIdx.x;
    int base = t * 4;
    int v[4]; int s = 0;
#pragma unroll
    for (int i = 0; i < 4; ++i) { v[i] = (base + i < N) ? cnt[base + i] : 0; s += v[i]; }
    sd[t] = s; __syncthreads();
    for (int d = 1; d < 256; d <<= 1) {
        int x = (t >= d) ? sd[t - d] : 0;
        __syncthreads();
        sd[t] += x;
        __syncthreads();
    }
    int p = sd[t] - s;
#pragma unroll
    for (int i = 0; i < 4; ++i) { if (base + i < N) offs[base + i] = p; p += v[i]; }
}

// ---------------- binning pass 2: block-local counting sort, coalesced flush ----------------
// ebuf entry packed: (src << 7) | (dst & 127)

__global__ __launch_bounds__(256) void bin2_kernel(const int* __restrict__ src,
                                                   const int* __restrict__ dst, int E, int NB,
                                                   const int* __restrict__ boff,
                                                   const int* __restrict__ blockBase,
                                                   int* __restrict__ ebuf) {
    __shared__ int h[MAXNB];
    __shared__ int intra[MAXNB];
    __shared__ int cursor[MAXNB];
    __shared__ int gbase[MAXNB];
    __shared__ int ps[256];
    __shared__ int sorted[CH];
    __shared__ unsigned char sbkt[CH];
    int t = threadIdx.x;
    int blk = blockIdx.x;
    for (int i = t; i < NB; i += 256) h[i] = 0;
    __syncthreads();
    int e0 = blk * CH;
#pragma unroll
    for (int i = 0; i < CH / 256; ++i) {
        int e = e0 + t + i * 256;
        if (e < E) atomicAdd(&h[dst[e] >> 7], 1);
    }
    __syncthreads();
    int base4 = t * 4;
    int v[4]; int s = 0;
#pragma unroll
    for (int k = 0; k < 4; ++k) { v[k] = (base4 + k < NB) ? h[base4 + k] : 0; s += v[k]; }
    ps[t] = s; __syncthreads();
    for (int d = 1; d < 256; d <<= 1) {
        int x = (t >= d) ? ps[t - d] : 0;
        __syncthreads();
        ps[t] += x;
        __syncthreads();
    }
    int p = ps[t] - s;
#pragma unroll
    for (int k = 0; k < 4; ++k) { if (base4 + k < NB) intra[base4 + k] = p; p += v[k]; }
    __syncthreads();
    for (int b = t; b < NB; b += 256) {
        cursor[b] = intra[b];
        gbase[b] = boff[b] + blockBase[(size_t)blk * MAXNB + b] - intra[b];
    }
    __syncthreads();
#pragma unroll
    for (int i = 0; i < CH / 256; ++i) {
        int e = e0 + t + i * 256;
        if (e < E) {
            int d = dst[e];
            int b = d >> 7;
            int pos = atomicAdd(&cursor[b], 1);
            sorted[pos] = (src[e] << 7) | (d & 127);
            sbkt[pos] = (unsigned char)(b & 255);   // low 8 bits; recover with bucket range
        }
    }
    __syncthreads();
    int lim = E - e0; if (lim > CH) lim = CH;
    for (int i = t; i < lim; i += 256) {
        int pr = sorted[i];
        // recover bucket: find b such that intra[b] <= i < intra[b]+h[b].
        // cheaper: we stored low 8 bits; disambiguate via binary search over intra.
        // simplest correct: binary search intra[] for i.
        int lo = 0, hi = NB - 1;
        while (lo < hi) {
            int mid = (lo + hi + 1) >> 1;
            if (intra[mid] <= i) lo = mid; else hi = mid - 1;
        }
        ebuf[(size_t)gbase[lo] + i] = pr;
    }
}

// ---------------- per-bucket CSR build + offs/cnt/dinv ----------------

__global__ __launch_bounds__(256) void csr_build_kernel(const int* __restrict__ ebuf,
                                                        const int* __restrict__ boff,
                                                        const int* __restrict__ gcnt,
                                                        int* __restrict__ csr,
                                                        int* __restrict__ offs,
                                                        int* __restrict__ cnt,
                                                        float* __restrict__ dinv, int N) {
    __shared__ int h[128];
    __shared__ int sc[128];
    __shared__ int loc[128];
    __shared__ int cur[128];
    int t = threadIdx.x, b = blockIdx.x;
    if (t < 128) h[t] = 0;
    __syncthreads();
    int o = boff[b], c = gcnt[b];
    for (int i = t; i < c; i += 256) atomicAdd(&h[ebuf[o + i] & 127], 1);
    __syncthreads();
    if (t < 128) sc[t] = h[t];
    __syncthreads();
    for (int d = 1; d < 128; d <<= 1) {
        int x = (t >= d && t < 128) ? sc[t - d] : 0;
        __syncthreads();
        if (t < 128) sc[t] += x;
        __syncthreads();
    }
    if (t < 128) { loc[t] = sc[t] - h[t]; cur[t] = loc[t]; }
    __syncthreads();
    for (int i = t; i < c; i += 256) {
        int pr = ebuf[o + i];
        int pos = atomicAdd(&cur[pr & 127], 1);
        csr[o + pos] = pr >> 7;
    }
    if (t < 128) {
        int v = b * 128 + t;
        if (v < N) {
            offs[v] = o + loc[t];
            cnt[v] = h[t];
            dinv[v] = rsqrtf((float)(h[t] + 1));
        }
    }
}

// ---------------- S-set: mark in-neighbors of roots + roots, compact ----------------

__global__ __launch_bounds__(256) void mark_kernel(const int* __restrict__ roots, int R,
                                                   const int* __restrict__ csr,
                                                   const int* __restrict__ offs,
                                                   const int* __restrict__ cnt,
                                                   unsigned char* __restrict__ flag) {
    int wid = (blockIdx.x * blockDim.x + threadIdx.x) >> 6;
    if (wid >= R) return;
    int lane = threadIdx.x & 63;
    int r = roots[wid];
    int o = offs[r], c = cnt[r];
    for (int i = lane; i < c; i += 64) flag[csr[o + i]] = 1;
    if (lane == 0) flag[r] = 1;
}

__global__ __launch_bounds__(256) void compact_kernel(const unsigned char* __restrict__ flag,
                                                      int N, int* __restrict__ nlist,
                                                      int* __restrict__ list,
                                                      int* __restrict__ inv) {
    int v = blockIdx.x * blockDim.x + threadIdx.x;
    if (v < N && flag[v]) {
        int p = atomicAdd(nlist, 1);
        list[p] = v;
        inv[v] = p;
    }
}

// ---------------- W split: W[K,128] fp32 -> WThi/WTlo[128][K] bf16 ----------------

__global__ void wsplit_kernel(const float* __restrict__ W, int K,
                              unsigned short* __restrict__ WThi,
                              unsigned short* __restrict__ WTlo) {
    int i = blockIdx.x * blockDim.x + threadIdx.x;
    if (i >= K * 128) return;
    int k = i >> 7, c = i & 127;
    float w = W[i];
    unsigned short hh = f2bf(w);
    float hf = __uint_as_float((unsigned)hh << 16);
    WThi[(size_t)c * K + k] = hh;
    WTlo[(size_t)c * K + k] = f2bf(w - hf);
}

// ---------------- split-bf16 MFMA GEMM: C[M,128] = A[M,K] @ W[K,128], fp16 out ----------------

__global__ __launch_bounds__(256) void gemm_mfma_kernel(const float* __restrict__ A,
                                                        const unsigned short* __restrict__ WThi,
                                                        const unsigned short* __restrict__ WTlo,
                                                        __half* __restrict__ C, int M,
                                                        const int* __restrict__ Mdev, int K) {
    if (Mdev) M = *Mdev;
    int row0 = blockIdx.x * 128;
    if (row0 >= M) return;
    __shared__ unsigned short Ah[128 * 32];
    __shared__ unsigned short Al[128 * 32];
    __shared__ unsigned short Bh[128 * 32];
    __shared__ unsigned short Bl[128 * 32];
    int t = threadIdx.x;
    int w = t >> 6, l = t & 63;
    int lr = l & 15, lk = l >> 4;

    float4v acc[2][8];
#pragma unroll
    for (int mf = 0; mf < 2; ++mf)
#pragma unroll
        for (int nf = 0; nf < 8; ++nf) acc[mf][nf] = (float4v){0.f, 0.f, 0.f, 0.f};

    for (int k0 = 0; k0 < K; k0 += 32) {
#pragma unroll
        for (int i = 0; i < 4; ++i) {
            int idx = t + i * 256;
            int r = idx >> 3, c4 = (idx & 7) * 4;
            int gr = row0 + r;
            float4 v = {0.f, 0.f, 0.f, 0.f};
            if (gr < M) v = *(const float4*)(A + (size_t)gr * K + k0 + c4);
            float fs[4] = {v.x, v.y, v.z, v.w};
            ushort4v hi, lo;
#pragma unroll
            for (int j = 0; j < 4; ++j) {
                unsigned short hh = f2bf(fs[j]);
                float hf = __uint_as_float((unsigned)hh << 16);
                hi[j] = hh;
                lo[j] = f2bf(fs[j] - hf);
            }
            *(ushort4v*)&Ah[r * 32 + c4] = hi;
            *(ushort4v*)&Al[r * 32 + c4] = lo;
        }
#pragma unroll
        for (int i = 0; i < 2; ++i) {
            int cidx = t + i * 256;
            int col = cidx >> 2, q = cidx & 3;
            ushort8v vh = *(const ushort8v*)(WThi + (size_t)col * K + k0 + q * 8);
            ushort8v vl = *(const ushort8v*)(WTlo + (size_t)col * K + k0 + q * 8);
            *(ushort8v*)&Bh[col * 32 + q * 8] = vh;
            *(ushort8v*)&Bl[col * 32 + q * 8] = vl;
        }
        __syncthreads();

        short8v ah0 = *(const short8v*)&Ah[(w * 32 + lr) * 32 + lk * 8];
        short8v al0 = *(const short8v*)&Al[(w * 32 + lr) * 32 + lk * 8];
        short8v ah1 = *(const short8v*)&Ah[(w * 32 + 16 + lr) * 32 + lk * 8];
        short8v al1 = *(const short8v*)&Al[(w * 32 + 16 + lr) * 32 + lk * 8];
#pragma unroll
        for (int nf = 0; nf < 8; ++nf) {
            short8v bh = *(const short8v*)&Bh[(nf * 16 + lr) * 32 + lk * 8];
            short8v bl = *(const short8v*)&Bl[(nf * 16 + lr) * 32 + lk * 8];
            acc[0][nf] = __builtin_amdgcn_mfma_f32_16x16x32_bf16(ah0, bh, acc[0][nf], 0, 0, 0);
            acc[0][nf] = __builtin_amdgcn_mfma_f32_16x16x32_bf16(ah0, bl, acc[0][nf], 0, 0, 0);
            acc[0][nf] = __builtin_amdgcn_mfma_f32_16x16x32_bf16(al0, bh, acc[0][nf], 0, 0, 0);
            acc[1][nf] = __builtin_amdgcn_mfma_f32_16x16x32_bf16(ah1, bh, acc[1][nf], 0, 0, 0);
            acc[1][nf] = __builtin_amdgcn_mfma_f32_16x16x32_bf16(ah1, bl, acc[1][nf], 0, 0, 0);
            acc[1][nf] = __builtin_amdgcn_mfma_f32_16x16x32_bf16(al1, bh, acc[1][nf], 0, 0, 0);
        }
        __syncthreads();
    }
#pragma unroll
    for (int mf = 0; mf < 2; ++mf)
#pragma unroll
        for (int nf = 0; nf < 8; ++nf)
#pragma unroll
            for (int r = 0; r < 4; ++r) {
                int grow = row0 + w * 32 + mf * 16 + lk * 4 + r;
                if (grow < M) C[(size_t)grow * 128 + nf * 16 + lr] = __float2half(acc[mf][nf][r]);
            }
}

// ---------------- aggregation: one wave per output row, fp16 gather ----------------

__global__ __launch_bounds__(256) void agg_kernel(const __half* __restrict__ xw,
                                                  const int* __restrict__ csr,
                                                  const int* __restrict__ offs,
                                                  const int* __restrict__ cnt,
                                                  const float* __restrict__ dinv,
                                                  const float* __restrict__ bias,
                                                  const int* __restrict__ nodelist,
                                                  const int* __restrict__ nwork_dev, int nwork,
                                                  float* __restrict__ out) {
    if (nwork_dev) nwork = *nwork_dev;
    int wid = (blockIdx.x * blockDim.x + threadIdx.x) >> 6;
    if (wid >= nwork) return;
    int lane = threadIdx.x & 63;
    int v = nodelist ? nodelist[wid] : wid;
    int o = offs[v];
    int c = cnt[v];
    float dv = dinv[v];
    float ax = 0.f, ay = 0.f;

    for (int base = 0; base < c; base += 64) {
        int rem = c - base; if (rem > 64) rem = 64;
        int li = base + lane; if (li >= c) li = c - 1;
        int s_l = csr[o + li];
        float d_l = dinv[s_l];
        int j = 0;
        for (; j + 4 <= rem; j += 4) {
            int s0 = __shfl(s_l, j);     int s1 = __shfl(s_l, j + 1);
            int s2 = __shfl(s_l, j + 2); int s3 = __shfl(s_l, j + 3);
            float e0 = __shfl(d_l, j);     float e1 = __shfl(d_l, j + 1);
            float e2 = __shfl(d_l, j + 2); float e3 = __shfl(d_l, j + 3);
            float2 v0 = __half22float2(*(const __half2*)(xw + (size_t)s0 * 128 + lane * 2));
            float2 v1 = __half22float2(*(const __half2*)(xw + (size_t)s1 * 128 + lane * 2));
            float2 v2 = __half22float2(*(const __half2*)(xw + (size_t)s2 * 128 + lane * 2));
            float2 v3 = __half22float2(*(const __half2*)(xw + (size_t)s3 * 128 + lane * 2));
            ax += e0 * v0.x + e1 * v1.x + e2 * v2.x + e3 * v3.x;
            ay += e0 * v0.y + e1 * v1.y + e2 * v2.y + e3 * v3.y;
        }
        for (; j < rem; ++j) {
            int s = __shfl(s_l, j);
            float e = __shfl(d_l, j);
            float2 vv = __half22float2(*(const __half2*)(xw + (size_t)s * 128 + lane * 2));
            ax += e * vv.x; ay += e * vv.y;
        }
    }
    float2 sv = __half22float2(*(const __half2*)(xw + (size_t)v * 128 + lane * 2));
    ax += dv * sv.x; ay += dv * sv.y;
    ax = dv * ax + bias[lane * 2];
    ay = dv * ay + bias[lane * 2 + 1];
    ax = ax > 0.f ? ax : expm1f(ax);
    ay = ay > 0.f ? ay : expm1f(ay);
    float2 res = {ax, ay};
    *(float2*)(out + (size_t)wid * 128 + lane * 2) = res;
}

// ---------------- root aggregation: fp16 gather via inv map ----------------

__global__ __launch_bounds__(256) void root_agg_kernel(const __half* __restrict__ xwc,
                                                       const int* __restrict__ inv,
                                                       const int* __restrict__ csr,
                                                       const int* __restrict__ offs,
                                                       const int* __restrict__ cnt,
                                                       const float* __restrict__ dinv,
                                                       const float* __restrict__ bias,
                                                       const int* __restrict__ roots, int R,
                                                       float* __restrict__ feat, int col0) {
    int wid = (blockIdx.x * blockDim.x + threadIdx.x) >> 6;
    if (wid >= R) return;
    int lane = threadIdx.x & 63;
    int r = roots[wid];
    int o = offs[r], c = cnt[r];
    float dv = dinv[r];
    float ax = 0.f, ay = 0.f;
    for (int base = 0; base < c; base += 64) {
        int rem = c - base; if (rem > 64) rem = 64;
        int li = base + lane; if (li >= c) li = c - 1;
        int s_l = csr[o + li];
        float d_l = dinv[s_l];
        int iv_l = inv[s_l];
        for (int j = 0; j < rem; ++j) {
            int iv = __shfl(iv_l, j);
            float e = __shfl(d_l, j);
            float2 vv = __half22float2(*(const __half2*)(xwc + (size_t)iv * 128 + lane * 2));
            ax += e * vv.x; ay += e * vv.y;
        }
    }
    int ivr = inv[r];
    float2 sv = __half22float2(*(const __half2*)(xwc + (size_t)ivr * 128 + lane * 2));
    ax += dv * sv.x; ay += dv * sv.y;
    ax = dv * ax + bias[lane * 2];
    ay = dv * ay + bias[lane * 2 + 1];
    ax = ax > 0.f ? ax : expm1f(ax);
    ay = ay > 0.f ? ay : expm1f(ay);
    float2 res = {ax, ay};
    *(float2*)(feat + (size_t)wid * 256 + col0 + lane * 2) = res;
}

// ---------------- head: logits + log_softmax over 2048 roots ----------------

__global__ __launch_bounds__(256) void head_kernel(const float* __restrict__ feat,
                                                   const float* __restrict__ fcw,
                                                   const float* __restrict__ fcb,
                                                   float* __restrict__ out, int R) {
    int wid = (blockIdx.x * blockDim.x + threadIdx.x) >> 6;
    if (wid >= R) return;
    int lane = threadIdx.x & 63;
    const float* fr = feat + (size_t)wid * 256;
    float a0 = 0.f, a1 = 0.f, a2 = 0.f, a3 = 0.f;
    for (int k = lane; k < 256; k += 64) {
        float f = fr[k];
        float4 w = *(const float4*)(fcw + k * 4);
        a0 += f * w.x; a1 += f * w.y; a2 += f * w.z; a3 += f * w.w;
    }
#pragma unroll
    for (int d = 1; d < 64; d <<= 1) {
        a0 += __shfl_xor(a0, d); a1 += __shfl_xor(a1, d);
        a2 += __shfl_xor(a2, d); a3 += __shfl_xor(a3, d);
    }
    if (lane == 0) {
        a0 += fcb[0]; a1 += fcb[1]; a2 += fcb[2]; a3 += fcb[3];
        float m = fmaxf(fmaxf(a0, a1), fmaxf(a2, a3));
        float s = expf(a0 - m) + expf(a1 - m) + expf(a2 - m) + expf(a3 - m);
        float ls = logf(s) + m;
        float4 rr = {a0 - ls, a1 - ls, a2 - ls, a3 - ls};
        *(float4*)(out + (size_t)wid * 4) = rr;
    }
}

// ---------------- launch ----------------

extern "C" void kernel_launch(void* const* d_in, const int* in_sizes, int n_in,
                              void* d_out, int out_size, void* d_ws, size_t ws_size,
                              hipStream_t stream) {
    const float* x    = (const float*)d_in[0];
    const int*   ei   = (const int*)d_in[1];
    const int*   bei  = (const int*)d_in[2];
    const int*   roots= (const int*)d_in[3];
    const float* w1 = (const float*)d_in[4];
    const float* b1 = (const float*)d_in[5];
    const float* w2 = (const float*)d_in[6];
    const float* b2 = (const float*)d_in[7];
    const float* w3 = (const float*)d_in[8];
    const float* b3 = (const float*)d_in[9];
    const float* w4 = (const float*)d_in[10];
    const float* b4 = (const float*)d_in[11];
    const float* fcw = (const float*)d_in[12];
    const float* fcb = (const float*)d_in[13];
    float* out = (float*)d_out;

    const int N = in_sizes[0] / 256;
    const int E = in_sizes[1] / 2;
    const int R = in_sizes[3];
    const int NB = (N + 127) >> 7;
    const int nblk = (E + CH - 1) / CH;

    char* ws = (char*)d_ws;
    size_t off = 0;
    auto alloc = [&](size_t b) { size_t o = off; off += (b + 255) & ~(size_t)255; return o; };
    __half* xw    = (__half*)(ws + alloc((size_t)N * 128 * 2));   // gemm1 out, fp16
    __half* xw2c  = (__half*)(ws + alloc((size_t)N * 128 * 2));   // gemm2 out (compacted), fp16
    float*  hc    = (float*)(ws + alloc((size_t)N * 128 * 4));    // h compacted, fp32
    int*   ebuf = (int*)(ws + alloc((size_t)E * 4));
    int*   csr  = (int*)(ws + alloc((size_t)E * 4));
    int*   blockBase = (int*)(ws + alloc((size_t)nblk * MAXNB * 4));
    int*   gcnt = (int*)(ws + alloc((size_t)MAXNB * 4));
    int*   boff = (int*)(ws + alloc((size_t)MAXNB * 4));
    int*   offs = (int*)(ws + alloc((size_t)N * 4));
    int*   cnt  = (int*)(ws + alloc((size_t)N * 4));
    float* dinv = (float*)(ws + alloc((size_t)N * 4));
    unsigned char* flag = (unsigned char*)(ws + alloc((size_t)N));
    int*   list = (int*)(ws + alloc((size_t)N * 4));
    int*   inv  = (int*)(ws + alloc((size_t)N * 4));
    int*   nlist = (int*)(ws + alloc(256));
    float* feat = (float*)(ws + alloc((size_t)R * 256 * 4));
    unsigned short* WThi = (unsigned short*)(ws + alloc((size_t)128 * 256 * 2));
    unsigned short* WTlo = (unsigned short*)(ws + alloc((size_t)128 * 256 * 2));

    for (int br = 0; br < 2; ++br) {
        const int* e    = (br == 0) ? ei : bei;
        const int* srcp = e;
        const int* dstp = e + E;
        const float* wA = (br == 0) ? w1 : w3;
        const float* bA = (br == 0) ? b1 : b3;
        const float* wB = (br == 0) ? w2 : w4;
        const float* bB = (br == 0) ? b2 : b4;

        hipMemsetAsync(gcnt, 0, (size_t)MAXNB * 4, stream);
        hipMemsetAsync(flag, 0, (size_t)N, stream);
        hipMemsetAsync(nlist, 0, 4, stream);
        bin1_kernel<<<nblk, 256, 0, stream>>>(dstp, E, NB, gcnt, blockBase);
        scan1_kernel<<<1, 256, 0, stream>>>(gcnt, NB, boff);
        bin2_kernel<<<nblk, 256, 0, stream>>>(srcp, dstp, E, NB, boff, blockBase, ebuf);
        csr_build_kernel<<<NB, 256, 0, stream>>>(ebuf, boff, gcnt, csr, offs, cnt, dinv, N);
        mark_kernel<<<(R * 64 + 255) / 256, 256, 0, stream>>>(roots, R, csr, offs, cnt, flag);
        compact_kernel<<<(N + 255) / 256, 256, 0, stream>>>(flag, N, nlist, list, inv);

        // layer 1: full gemm, aggregation only at S-set (list), compacted h
        wsplit_kernel<<<(256 * 128 + 255) / 256, 256, 0, stream>>>(wA, 256, WThi, WTlo);
        gemm_mfma_kernel<<<(N + 127) / 128, 256, 0, stream>>>(x, WThi, WTlo, xw, N, nullptr, 256);
        agg_kernel<<<((size_t)N * 64 + 255) / 256, 256, 0, stream>>>(
            xw, csr, offs, cnt, dinv, bA, list, nlist, N, hc);
        // layer 2: gemm over compacted rows, root aggregation via inv map
        wsplit_kernel<<<(128 * 128 + 255) / 256, 256, 0, stream>>>(wB, 128, WThi, WTlo);
        gemm_mfma_kernel<<<(N + 127) / 128, 256, 0, stream>>>(hc, WThi, WTlo, xw2c, N, nlist, 128);
        root_agg_kernel<<<((size_t)R * 64 + 255) / 256, 256, 0, stream>>>(
            xw2c, inv, csr, offs, cnt, dinv, bB, roots, R, feat, br * 128);
    }
    head_kernel<<<((size_t)R * 64 + 255) / 256, 256, 0, stream>>>(feat, fcw, fcb, out, R);
}

// Round 6
// 558.323 us; speedup vs baseline: 5.9739x; 1.0254x over previous
//
#include <hip/hip_runtime.h>
#include <hip/hip_fp16.h>
#include <math.h>

typedef __attribute__((ext_vector_type(8))) short short8v;
typedef __attribute__((ext_vector_type(4))) float float4v;
typedef __attribute__((ext_vector_type(8))) unsigned short ushort8v;

#define CH 4096     // edges per binning block
#define MAXNB 800   // max buckets (100096/128 = 782)

// swizzled 16B-chunk position within a 64B row (4 chunks): kills 8-way bank conflicts
#define SWZ(row, ck) ((ck) ^ (((row) >> 1) & 3))

__device__ inline unsigned short f2bf(float f) {
    unsigned u = __float_as_uint(f);
    return (unsigned short)((u + 0x7FFFu + ((u >> 16) & 1u)) >> 16);
}

// ---------------- binning pass 1 ----------------

__global__ __launch_bounds__(256) void bin1_kernel(const int* __restrict__ dst, int E, int NB,
                                                   int* __restrict__ gcnt,
                                                   int* __restrict__ blockBase) {
    __shared__ int h[MAXNB];
    int t = threadIdx.x;
    for (int i = t; i < NB; i += 256) h[i] = 0;
    __syncthreads();
    int e0 = blockIdx.x * CH;
#pragma unroll
    for (int i = 0; i < CH / 256; ++i) {
        int e = e0 + t + i * 256;
        if (e < E) atomicAdd(&h[dst[e] >> 7], 1);
    }
    __syncthreads();
    for (int b = t; b < NB; b += 256) {
        int c = h[b];
        int old = atomicAdd(&gcnt[b], c);
        blockBase[(size_t)blockIdx.x * MAXNB + b] = old;
    }
}

// ---------------- exclusive scan (single block, NB <= 1024) ----------------

__global__ void scan1_kernel(const int* __restrict__ cnt, int N,
                             int* __restrict__ offs) {
    __shared__ int sd[256];
    int t = threadIdx.x;
    int base = t * 4;
    int v[4]; int s = 0;
#pragma unroll
    for (int i = 0; i < 4; ++i) { v[i] = (base + i < N) ? cnt[base + i] : 0; s += v[i]; }
    sd[t] = s; __syncthreads();
    for (int d = 1; d < 256; d <<= 1) {
        int x = (t >= d) ? sd[t - d] : 0;
        __syncthreads();
        sd[t] += x;
        __syncthreads();
    }
    int p = sd[t] - s;
#pragma unroll
    for (int i = 0; i < 4; ++i) { if (base + i < N) offs[base + i] = p; p += v[i]; }
}

// ---------------- binning pass 2: block-local counting sort ----------------
// ebuf entry packed: (src << 7) | (dst & 127)

__global__ __launch_bounds__(256) void bin2_kernel(const int* __restrict__ src,
                                                   const int* __restrict__ dst, int E, int NB,
                                                   const int* __restrict__ boff,
                                                   const int* __restrict__ blockBase,
                                                   int* __restrict__ ebuf) {
    __shared__ int h[MAXNB];
    __shared__ int intra[MAXNB];
    __shared__ int cursor[MAXNB];
    __shared__ int gbase[MAXNB];
    __shared__ int ps[256];
    __shared__ int sorted[CH];
    int t = threadIdx.x;
    int blk = blockIdx.x;
    for (int i = t; i < NB; i += 256) h[i] = 0;
    __syncthreads();
    int e0 = blk * CH;
#pragma unroll
    for (int i = 0; i < CH / 256; ++i) {
        int e = e0 + t + i * 256;
        if (e < E) atomicAdd(&h[dst[e] >> 7], 1);
    }
    __syncthreads();
    int base4 = t * 4;
    int v[4]; int s = 0;
#pragma unroll
    for (int k = 0; k < 4; ++k) { v[k] = (base4 + k < NB) ? h[base4 + k] : 0; s += v[k]; }
    ps[t] = s; __syncthreads();
    for (int d = 1; d < 256; d <<= 1) {
        int x = (t >= d) ? ps[t - d] : 0;
        __syncthreads();
        ps[t] += x;
        __syncthreads();
    }
    int p = ps[t] - s;
#pragma unroll
    for (int k = 0; k < 4; ++k) { if (base4 + k < NB) intra[base4 + k] = p; p += v[k]; }
    __syncthreads();
    for (int b = t; b < NB; b += 256) {
        cursor[b] = intra[b];
        gbase[b] = boff[b] + blockBase[(size_t)blk * MAXNB + b] - intra[b];
    }
    __syncthreads();
#pragma unroll
    for (int i = 0; i < CH / 256; ++i) {
        int e = e0 + t + i * 256;
        if (e < E) {
            int d = dst[e];
            int b = d >> 7;
            int pos = atomicAdd(&cursor[b], 1);
            sorted[pos] = (src[e] << 7) | (d & 127);
        }
    }
    __syncthreads();
    int lim = E - e0; if (lim > CH) lim = CH;
    for (int i = t; i < lim; i += 256) {
        int pr = sorted[i];
        int lo = 0, hi = NB - 1;
        while (lo < hi) {
            int mid = (lo + hi + 1) >> 1;
            if (intra[mid] <= i) lo = mid; else hi = mid - 1;
        }
        ebuf[(size_t)gbase[lo] + i] = pr;
    }
}

// ---------------- per-bucket CSR build + offs/cnt/dinv ----------------

__global__ __launch_bounds__(256) void csr_build_kernel(const int* __restrict__ ebuf,
                                                        const int* __restrict__ boff,
                                                        const int* __restrict__ gcnt,
                                                        int* __restrict__ csr,
                                                        int* __restrict__ offs,
                                                        int* __restrict__ cnt,
                                                        float* __restrict__ dinv, int N) {
    __shared__ int h[128];
    __shared__ int sc[128];
    __shared__ int loc[128];
    __shared__ int cur[128];
    int t = threadIdx.x, b = blockIdx.x;
    if (t < 128) h[t] = 0;
    __syncthreads();
    int o = boff[b], c = gcnt[b];
    for (int i = t; i < c; i += 256) atomicAdd(&h[ebuf[o + i] & 127], 1);
    __syncthreads();
    if (t < 128) sc[t] = h[t];
    __syncthreads();
    for (int d = 1; d < 128; d <<= 1) {
        int x = (t >= d && t < 128) ? sc[t - d] : 0;
        __syncthreads();
        if (t < 128) sc[t] += x;
        __syncthreads();
    }
    if (t < 128) { loc[t] = sc[t] - h[t]; cur[t] = loc[t]; }
    __syncthreads();
    for (int i = t; i < c; i += 256) {
        int pr = ebuf[o + i];
        int pos = atomicAdd(&cur[pr & 127], 1);
        csr[o + pos] = pr >> 7;
    }
    if (t < 128) {
        int v = b * 128 + t;
        if (v < N) {
            offs[v] = o + loc[t];
            cnt[v] = h[t];
            dinv[v] = rsqrtf((float)(h[t] + 1));
        }
    }
}

// ---------------- S-set: mark in-neighbors of roots + roots, compact ----------------

__global__ __launch_bounds__(256) void mark_kernel(const int* __restrict__ roots, int R,
                                                   const int* __restrict__ csr,
                                                   const int* __restrict__ offs,
                                                   const int* __restrict__ cnt,
                                                   unsigned char* __restrict__ flag) {
    int wid = (blockIdx.x * blockDim.x + threadIdx.x) >> 6;
    if (wid >= R) return;
    int lane = threadIdx.x & 63;
    int r = roots[wid];
    int o = offs[r], c = cnt[r];
    for (int i = lane; i < c; i += 64) flag[csr[o + i]] = 1;
    if (lane == 0) flag[r] = 1;
}

__global__ __launch_bounds__(256) void compact_kernel(const unsigned char* __restrict__ flag,
                                                      int N, int* __restrict__ nlist,
                                                      int* __restrict__ list,
                                                      int* __restrict__ inv) {
    int v = blockIdx.x * blockDim.x + threadIdx.x;
    if (v < N && flag[v]) {
        int p = atomicAdd(nlist, 1);
        list[p] = v;
        inv[v] = p;
    }
}

// ---------------- W split: W[K,128] fp32 -> WThi/WTlo[128][K] bf16 ----------------

__global__ void wsplit_kernel(const float* __restrict__ W, int K,
                              unsigned short* __restrict__ WThi,
                              unsigned short* __restrict__ WTlo) {
    int i = blockIdx.x * blockDim.x + threadIdx.x;
    if (i >= K * 128) return;
    int k = i >> 7, c = i & 127;
    float w = W[i];
    unsigned short hh = f2bf(w);
    float hf = __uint_as_float((unsigned)hh << 16);
    WThi[(size_t)c * K + k] = hh;
    WTlo[(size_t)c * K + k] = f2bf(w - hf);
}

// ---------------- dual-branch split-bf16 MFMA GEMM (layer 1, K=256) ----------------
// C0 = A@W0, C1 = A@W1 in one pass: A staged/converted ONCE.

__global__ __launch_bounds__(256) void gemm1_dual_kernel(const float* __restrict__ A,
                                                         const unsigned short* __restrict__ Bhi0,
                                                         const unsigned short* __restrict__ Blo0,
                                                         const unsigned short* __restrict__ Bhi1,
                                                         const unsigned short* __restrict__ Blo1,
                                                         __half* __restrict__ C0,
                                                         __half* __restrict__ C1,
                                                         int M, int K) {
    __shared__ unsigned short Ah[128 * 32];
    __shared__ unsigned short Al[128 * 32];
    __shared__ unsigned short Bh[2][128 * 32];
    __shared__ unsigned short Bl[2][128 * 32];
    int t = threadIdx.x;
    int w = t >> 6, l = t & 63;
    int lr = l & 15, lk = l >> 4;
    int row0 = blockIdx.x * 128;

    float4v acc[2][2][8];
#pragma unroll
    for (int b = 0; b < 2; ++b)
#pragma unroll
        for (int mf = 0; mf < 2; ++mf)
#pragma unroll
            for (int nf = 0; nf < 8; ++nf) acc[b][mf][nf] = (float4v){0.f, 0.f, 0.f, 0.f};

    for (int k0 = 0; k0 < K; k0 += 32) {
        // A tile 128x32 fp32 -> hi/lo bf16, 16B swizzled chunks (512 chunks, 2/thread)
#pragma unroll
        for (int i = 0; i < 2; ++i) {
            int idx = t + i * 256;
            int r = idx >> 2, ck = idx & 3;
            int gr = row0 + r;
            float4 v0 = {0.f, 0.f, 0.f, 0.f}, v1 = {0.f, 0.f, 0.f, 0.f};
            if (gr < M) {
                const float* p = A + (size_t)gr * K + k0 + ck * 8;
                v0 = *(const float4*)p;
                v1 = *(const float4*)(p + 4);
            }
            float fs[8] = {v0.x, v0.y, v0.z, v0.w, v1.x, v1.y, v1.z, v1.w};
            ushort8v hi, lo;
#pragma unroll
            for (int j = 0; j < 8; ++j) {
                unsigned short hh = f2bf(fs[j]);
                hi[j] = hh;
                lo[j] = f2bf(fs[j] - __uint_as_float((unsigned)hh << 16));
            }
            int pos = r * 32 + SWZ(r, ck) * 8;
            *(ushort8v*)&Ah[pos] = hi;
            *(ushort8v*)&Al[pos] = lo;
        }
        // B tiles for both branches (pre-split bf16), swizzled
#pragma unroll
        for (int i = 0; i < 2; ++i) {
            int idx = t + i * 256;
            int col = idx >> 2, ck = idx & 3;
            size_t g = (size_t)col * K + k0 + ck * 8;
            int pos = col * 32 + SWZ(col, ck) * 8;
            *(ushort8v*)&Bh[0][pos] = *(const ushort8v*)(Bhi0 + g);
            *(ushort8v*)&Bl[0][pos] = *(const ushort8v*)(Blo0 + g);
            *(ushort8v*)&Bh[1][pos] = *(const ushort8v*)(Bhi1 + g);
            *(ushort8v*)&Bl[1][pos] = *(const ushort8v*)(Blo1 + g);
        }
        __syncthreads();

        int ar0 = w * 32 + lr, ar1 = w * 32 + 16 + lr;
        short8v ah0 = *(const short8v*)&Ah[ar0 * 32 + SWZ(ar0, lk) * 8];
        short8v al0 = *(const short8v*)&Al[ar0 * 32 + SWZ(ar0, lk) * 8];
        short8v ah1 = *(const short8v*)&Ah[ar1 * 32 + SWZ(ar1, lk) * 8];
        short8v al1 = *(const short8v*)&Al[ar1 * 32 + SWZ(ar1, lk) * 8];
#pragma unroll
        for (int nf = 0; nf < 8; ++nf) {
            int brow = nf * 16 + lr;
            int bpos = brow * 32 + SWZ(brow, lk) * 8;
            short8v bh0 = *(const short8v*)&Bh[0][bpos];
            short8v bl0 = *(const short8v*)&Bl[0][bpos];
            acc[0][0][nf] = __builtin_amdgcn_mfma_f32_16x16x32_bf16(ah0, bh0, acc[0][0][nf], 0, 0, 0);
            acc[0][0][nf] = __builtin_amdgcn_mfma_f32_16x16x32_bf16(ah0, bl0, acc[0][0][nf], 0, 0, 0);
            acc[0][0][nf] = __builtin_amdgcn_mfma_f32_16x16x32_bf16(al0, bh0, acc[0][0][nf], 0, 0, 0);
            acc[0][1][nf] = __builtin_amdgcn_mfma_f32_16x16x32_bf16(ah1, bh0, acc[0][1][nf], 0, 0, 0);
            acc[0][1][nf] = __builtin_amdgcn_mfma_f32_16x16x32_bf16(ah1, bl0, acc[0][1][nf], 0, 0, 0);
            acc[0][1][nf] = __builtin_amdgcn_mfma_f32_16x16x32_bf16(al1, bh0, acc[0][1][nf], 0, 0, 0);
            short8v bh1 = *(const short8v*)&Bh[1][bpos];
            short8v bl1 = *(const short8v*)&Bl[1][bpos];
            acc[1][0][nf] = __builtin_amdgcn_mfma_f32_16x16x32_bf16(ah0, bh1, acc[1][0][nf], 0, 0, 0);
            acc[1][0][nf] = __builtin_amdgcn_mfma_f32_16x16x32_bf16(ah0, bl1, acc[1][0][nf], 0, 0, 0);
            acc[1][0][nf] = __builtin_amdgcn_mfma_f32_16x16x32_bf16(al0, bh1, acc[1][0][nf], 0, 0, 0);
            acc[1][1][nf] = __builtin_amdgcn_mfma_f32_16x16x32_bf16(ah1, bh1, acc[1][1][nf], 0, 0, 0);
            acc[1][1][nf] = __builtin_amdgcn_mfma_f32_16x16x32_bf16(ah1, bl1, acc[1][1][nf], 0, 0, 0);
            acc[1][1][nf] = __builtin_amdgcn_mfma_f32_16x16x32_bf16(al1, bh1, acc[1][1][nf], 0, 0, 0);
        }
        __syncthreads();
    }
#pragma unroll
    for (int mf = 0; mf < 2; ++mf)
#pragma unroll
        for (int nf = 0; nf < 8; ++nf)
#pragma unroll
            for (int r = 0; r < 4; ++r) {
                int grow = row0 + w * 32 + mf * 16 + lk * 4 + r;
                if (grow < M) {
                    C0[(size_t)grow * 128 + nf * 16 + lr] = __float2half(acc[0][mf][nf][r]);
                    C1[(size_t)grow * 128 + nf * 16 + lr] = __float2half(acc[1][mf][nf][r]);
                }
            }
}

// ---------------- single split-bf16 MFMA GEMM (layer 2), swizzled LDS ----------------

__global__ __launch_bounds__(256) void gemm_mfma_kernel(const float* __restrict__ A,
                                                        const unsigned short* __restrict__ WThi,
                                                        const unsigned short* __restrict__ WTlo,
                                                        __half* __restrict__ C, int M,
                                                        const int* __restrict__ Mdev, int K) {
    if (Mdev) M = *Mdev;
    int row0 = blockIdx.x * 128;
    if (row0 >= M) return;
    __shared__ unsigned short Ah[128 * 32];
    __shared__ unsigned short Al[128 * 32];
    __shared__ unsigned short Bh[128 * 32];
    __shared__ unsigned short Bl[128 * 32];
    int t = threadIdx.x;
    int w = t >> 6, l = t & 63;
    int lr = l & 15, lk = l >> 4;

    float4v acc[2][8];
#pragma unroll
    for (int mf = 0; mf < 2; ++mf)
#pragma unroll
        for (int nf = 0; nf < 8; ++nf) acc[mf][nf] = (float4v){0.f, 0.f, 0.f, 0.f};

    for (int k0 = 0; k0 < K; k0 += 32) {
#pragma unroll
        for (int i = 0; i < 2; ++i) {
            int idx = t + i * 256;
            int r = idx >> 2, ck = idx & 3;
            int gr = row0 + r;
            float4 v0 = {0.f, 0.f, 0.f, 0.f}, v1 = {0.f, 0.f, 0.f, 0.f};
            if (gr < M) {
                const float* p = A + (size_t)gr * K + k0 + ck * 8;
                v0 = *(const float4*)p;
                v1 = *(const float4*)(p + 4);
            }
            float fs[8] = {v0.x, v0.y, v0.z, v0.w, v1.x, v1.y, v1.z, v1.w};
            ushort8v hi, lo;
#pragma unroll
            for (int j = 0; j < 8; ++j) {
                unsigned short hh = f2bf(fs[j]);
                hi[j] = hh;
                lo[j] = f2bf(fs[j] - __uint_as_float((unsigned)hh << 16));
            }
            int pos = r * 32 + SWZ(r, ck) * 8;
            *(ushort8v*)&Ah[pos] = hi;
            *(ushort8v*)&Al[pos] = lo;
        }
#pragma unroll
        for (int i = 0; i < 2; ++i) {
            int idx = t + i * 256;
            int col = idx >> 2, ck = idx & 3;
            size_t g = (size_t)col * K + k0 + ck * 8;
            int pos = col * 32 + SWZ(col, ck) * 8;
            *(ushort8v*)&Bh[pos] = *(const ushort8v*)(WThi + g);
            *(ushort8v*)&Bl[pos] = *(const ushort8v*)(WTlo + g);
        }
        __syncthreads();

        int ar0 = w * 32 + lr, ar1 = w * 32 + 16 + lr;
        short8v ah0 = *(const short8v*)&Ah[ar0 * 32 + SWZ(ar0, lk) * 8];
        short8v al0 = *(const short8v*)&Al[ar0 * 32 + SWZ(ar0, lk) * 8];
        short8v ah1 = *(const short8v*)&Ah[ar1 * 32 + SWZ(ar1, lk) * 8];
        short8v al1 = *(const short8v*)&Al[ar1 * 32 + SWZ(ar1, lk) * 8];
#pragma unroll
        for (int nf = 0; nf < 8; ++nf) {
            int brow = nf * 16 + lr;
            int bpos = brow * 32 + SWZ(brow, lk) * 8;
            short8v bh = *(const short8v*)&Bh[bpos];
            short8v bl = *(const short8v*)&Bl[bpos];
            acc[0][nf] = __builtin_amdgcn_mfma_f32_16x16x32_bf16(ah0, bh, acc[0][nf], 0, 0, 0);
            acc[0][nf] = __builtin_amdgcn_mfma_f32_16x16x32_bf16(ah0, bl, acc[0][nf], 0, 0, 0);
            acc[0][nf] = __builtin_amdgcn_mfma_f32_16x16x32_bf16(al0, bh, acc[0][nf], 0, 0, 0);
            acc[1][nf] = __builtin_amdgcn_mfma_f32_16x16x32_bf16(ah1, bh, acc[1][nf], 0, 0, 0);
            acc[1][nf] = __builtin_amdgcn_mfma_f32_16x16x32_bf16(ah1, bl, acc[1][nf], 0, 0, 0);
            acc[1][nf] = __builtin_amdgcn_mfma_f32_16x16x32_bf16(al1, bh, acc[1][nf], 0, 0, 0);
        }
        __syncthreads();
    }
#pragma unroll
    for (int mf = 0; mf < 2; ++mf)
#pragma unroll
        for (int nf = 0; nf < 8; ++nf)
#pragma unroll
            for (int r = 0; r < 4; ++r) {
                int grow = row0 + w * 32 + mf * 16 + lk * 4 + r;
                if (grow < M) C[(size_t)grow * 128 + nf * 16 + lr] = __float2half(acc[mf][nf][r]);
            }
}

// ---------------- aggregation: one wave per output row, fp16 gather ----------------

__global__ __launch_bounds__(256) void agg_kernel(const __half* __restrict__ xw,
                                                  const int* __restrict__ csr,
                                                  const int* __restrict__ offs,
                                                  const int* __restrict__ cnt,
                                                  const float* __restrict__ dinv,
                                                  const float* __restrict__ bias,
                                                  const int* __restrict__ nodelist,
                                                  const int* __restrict__ nwork_dev, int nwork,
                                                  float* __restrict__ out) {
    if (nwork_dev) nwork = *nwork_dev;
    int wid = (blockIdx.x * blockDim.x + threadIdx.x) >> 6;
    if (wid >= nwork) return;
    int lane = threadIdx.x & 63;
    int v = nodelist ? nodelist[wid] : wid;
    int o = offs[v];
    int c = cnt[v];
    float dv = dinv[v];
    float ax = 0.f, ay = 0.f;

    for (int base = 0; base < c; base += 64) {
        int rem = c - base; if (rem > 64) rem = 64;
        int li = base + lane; if (li >= c) li = c - 1;
        int s_l = csr[o + li];
        float d_l = dinv[s_l];
        int j = 0;
        for (; j + 4 <= rem; j += 4) {
            int s0 = __shfl(s_l, j);     int s1 = __shfl(s_l, j + 1);
            int s2 = __shfl(s_l, j + 2); int s3 = __shfl(s_l, j + 3);
            float e0 = __shfl(d_l, j);     float e1 = __shfl(d_l, j + 1);
            float e2 = __shfl(d_l, j + 2); float e3 = __shfl(d_l, j + 3);
            float2 v0 = __half22float2(*(const __half2*)(xw + (size_t)s0 * 128 + lane * 2));
            float2 v1 = __half22float2(*(const __half2*)(xw + (size_t)s1 * 128 + lane * 2));
            float2 v2 = __half22float2(*(const __half2*)(xw + (size_t)s2 * 128 + lane * 2));
            float2 v3 = __half22float2(*(const __half2*)(xw + (size_t)s3 * 128 + lane * 2));
            ax += e0 * v0.x + e1 * v1.x + e2 * v2.x + e3 * v3.x;
            ay += e0 * v0.y + e1 * v1.y + e2 * v2.y + e3 * v3.y;
        }
        for (; j < rem; ++j) {
            int s = __shfl(s_l, j);
            float e = __shfl(d_l, j);
            float2 vv = __half22float2(*(const __half2*)(xw + (size_t)s * 128 + lane * 2));
            ax += e * vv.x; ay += e * vv.y;
        }
    }
    float2 sv = __half22float2(*(const __half2*)(xw + (size_t)v * 128 + lane * 2));
    ax += dv * sv.x; ay += dv * sv.y;
    ax = dv * ax + bias[lane * 2];
    ay = dv * ay + bias[lane * 2 + 1];
    ax = ax > 0.f ? ax : expm1f(ax);
    ay = ay > 0.f ? ay : expm1f(ay);
    float2 res = {ax, ay};
    *(float2*)(out + (size_t)wid * 128 + lane * 2) = res;
}

// ---------------- root aggregation: fp16 gather via inv map ----------------

__global__ __launch_bounds__(256) void root_agg_kernel(const __half* __restrict__ xwc,
                                                       const int* __restrict__ inv,
                                                       const int* __restrict__ csr,
                                                       const int* __restrict__ offs,
                                                       const int* __restrict__ cnt,
                                                       const float* __restrict__ dinv,
                                                       const float* __restrict__ bias,
                                                       const int* __restrict__ roots, int R,
                                                       float* __restrict__ feat, int col0) {
    int wid = (blockIdx.x * blockDim.x + threadIdx.x) >> 6;
    if (wid >= R) return;
    int lane = threadIdx.x & 63;
    int r = roots[wid];
    int o = offs[r], c = cnt[r];
    float dv = dinv[r];
    float ax = 0.f, ay = 0.f;
    for (int base = 0; base < c; base += 64) {
        int rem = c - base; if (rem > 64) rem = 64;
        int li = base + lane; if (li >= c) li = c - 1;
        int s_l = csr[o + li];
        float d_l = dinv[s_l];
        int iv_l = inv[s_l];
        for (int j = 0; j < rem; ++j) {
            int iv = __shfl(iv_l, j);
            float e = __shfl(d_l, j);
            float2 vv = __half22float2(*(const __half2*)(xwc + (size_t)iv * 128 + lane * 2));
            ax += e * vv.x; ay += e * vv.y;
        }
    }
    int ivr = inv[r];
    float2 sv = __half22float2(*(const __half2*)(xwc + (size_t)ivr * 128 + lane * 2));
    ax += dv * sv.x; ay += dv * sv.y;
    ax = dv * ax + bias[lane * 2];
    ay = dv * ay + bias[lane * 2 + 1];
    ax = ax > 0.f ? ax : expm1f(ax);
    ay = ay > 0.f ? ay : expm1f(ay);
    float2 res = {ax, ay};
    *(float2*)(feat + (size_t)wid * 256 + col0 + lane * 2) = res;
}

// ---------------- head: logits + log_softmax over 2048 roots ----------------

__global__ __launch_bounds__(256) void head_kernel(const float* __restrict__ feat,
                                                   const float* __restrict__ fcw,
                                                   const float* __restrict__ fcb,
                                                   float* __restrict__ out, int R) {
    int wid = (blockIdx.x * blockDim.x + threadIdx.x) >> 6;
    if (wid >= R) return;
    int lane = threadIdx.x & 63;
    const float* fr = feat + (size_t)wid * 256;
    float a0 = 0.f, a1 = 0.f, a2 = 0.f, a3 = 0.f;
    for (int k = lane; k < 256; k += 64) {
        float f = fr[k];
        float4 w = *(const float4*)(fcw + k * 4);
        a0 += f * w.x; a1 += f * w.y; a2 += f * w.z; a3 += f * w.w;
    }
#pragma unroll
    for (int d = 1; d < 64; d <<= 1) {
        a0 += __shfl_xor(a0, d); a1 += __shfl_xor(a1, d);
        a2 += __shfl_xor(a2, d); a3 += __shfl_xor(a3, d);
    }
    if (lane == 0) {
        a0 += fcb[0]; a1 += fcb[1]; a2 += fcb[2]; a3 += fcb[3];
        float m = fmaxf(fmaxf(a0, a1), fmaxf(a2, a3));
        float s = expf(a0 - m) + expf(a1 - m) + expf(a2 - m) + expf(a3 - m);
        float ls = logf(s) + m;
        float4 rr = {a0 - ls, a1 - ls, a2 - ls, a3 - ls};
        *(float4*)(out + (size_t)wid * 4) = rr;
    }
}

// ---------------- launch ----------------

extern "C" void kernel_launch(void* const* d_in, const int* in_sizes, int n_in,
                              void* d_out, int out_size, void* d_ws, size_t ws_size,
                              hipStream_t stream) {
    const float* x    = (const float*)d_in[0];
    const int*   ei   = (const int*)d_in[1];
    const int*   bei  = (const int*)d_in[2];
    const int*   roots= (const int*)d_in[3];
    const float* w1 = (const float*)d_in[4];
    const float* b1 = (const float*)d_in[5];
    const float* w2 = (const float*)d_in[6];
    const float* b2 = (const float*)d_in[7];
    const float* w3 = (const float*)d_in[8];
    const float* b3 = (const float*)d_in[9];
    const float* w4 = (const float*)d_in[10];
    const float* b4 = (const float*)d_in[11];
    const float* fcw = (const float*)d_in[12];
    const float* fcb = (const float*)d_in[13];
    float* out = (float*)d_out;

    const int N = in_sizes[0] / 256;
    const int E = in_sizes[1] / 2;
    const int R = in_sizes[3];
    const int NB = (N + 127) >> 7;
    const int nblk = (E + CH - 1) / CH;

    char* ws = (char*)d_ws;
    size_t off = 0;
    auto alloc = [&](size_t b) { size_t o = off; off += (b + 255) & ~(size_t)255; return o; };
    __half* xw0   = (__half*)(ws + alloc((size_t)N * 128 * 2));
    __half* xw1   = (__half*)(ws + alloc((size_t)N * 128 * 2));
    __half* xw2c  = (__half*)(ws + alloc((size_t)N * 128 * 2));
    float*  hc    = (float*)(ws + alloc((size_t)N * 128 * 4));
    int*   ebuf = (int*)(ws + alloc((size_t)E * 4));
    int*   blockBase = (int*)(ws + alloc((size_t)nblk * MAXNB * 4));
    int*   gcnt = (int*)(ws + alloc((size_t)MAXNB * 4));
    int*   boff = (int*)(ws + alloc((size_t)MAXNB * 4));
    int*   csrA[2]; int* offsA[2]; int* cntA[2]; float* dinvA[2];
    int*   listA[2]; int* invA[2]; int* nlistA[2];
    unsigned char* flagA[2];
    for (int br = 0; br < 2; ++br) {
        csrA[br]  = (int*)(ws + alloc((size_t)E * 4));
        offsA[br] = (int*)(ws + alloc((size_t)N * 4));
        cntA[br]  = (int*)(ws + alloc((size_t)N * 4));
        dinvA[br] = (float*)(ws + alloc((size_t)N * 4));
        flagA[br] = (unsigned char*)(ws + alloc((size_t)N));
        listA[br] = (int*)(ws + alloc((size_t)N * 4));
        invA[br]  = (int*)(ws + alloc((size_t)N * 4));
        nlistA[br]= (int*)(ws + alloc(256));
    }
    float* feat = (float*)(ws + alloc((size_t)R * 256 * 4));
    unsigned short* WThi[4]; unsigned short* WTlo[4];
    for (int i = 0; i < 4; ++i) {
        int K = (i < 2) ? 256 : 128;
        WThi[i] = (unsigned short*)(ws + alloc((size_t)128 * K * 2));
        WTlo[i] = (unsigned short*)(ws + alloc((size_t)128 * K * 2));
    }

    // per-branch graph preprocessing
    for (int br = 0; br < 2; ++br) {
        const int* e    = (br == 0) ? ei : bei;
        const int* srcp = e;
        const int* dstp = e + E;
        hipMemsetAsync(gcnt, 0, (size_t)MAXNB * 4, stream);
        hipMemsetAsync(flagA[br], 0, (size_t)N, stream);
        hipMemsetAsync(nlistA[br], 0, 4, stream);
        bin1_kernel<<<nblk, 256, 0, stream>>>(dstp, E, NB, gcnt, blockBase);
        scan1_kernel<<<1, 256, 0, stream>>>(gcnt, NB, boff);
        bin2_kernel<<<nblk, 256, 0, stream>>>(srcp, dstp, E, NB, boff, blockBase, ebuf);
        csr_build_kernel<<<NB, 256, 0, stream>>>(ebuf, boff, gcnt, csrA[br], offsA[br],
                                                 cntA[br], dinvA[br], N);
        mark_kernel<<<(R * 64 + 255) / 256, 256, 0, stream>>>(roots, R, csrA[br], offsA[br],
                                                              cntA[br], flagA[br]);
        compact_kernel<<<(N + 255) / 256, 256, 0, stream>>>(flagA[br], N, nlistA[br],
                                                            listA[br], invA[br]);
    }

    // weight splits
    wsplit_kernel<<<(256 * 128 + 255) / 256, 256, 0, stream>>>(w1, 256, WThi[0], WTlo[0]);
    wsplit_kernel<<<(256 * 128 + 255) / 256, 256, 0, stream>>>(w3, 256, WThi[1], WTlo[1]);
    wsplit_kernel<<<(128 * 128 + 255) / 256, 256, 0, stream>>>(w2, 128, WThi[2], WTlo[2]);
    wsplit_kernel<<<(128 * 128 + 255) / 256, 256, 0, stream>>>(w4, 128, WThi[3], WTlo[3]);

    // layer-1 GEMM for both branches, A staged once
    gemm1_dual_kernel<<<(N + 127) / 128, 256, 0, stream>>>(
        x, WThi[0], WTlo[0], WThi[1], WTlo[1], xw0, xw1, N, 256);

    for (int br = 0; br < 2; ++br) {
        const __half* xwb = (br == 0) ? xw0 : xw1;
        const float* bA = (br == 0) ? b1 : b3;
        const float* bB = (br == 0) ? b2 : b4;
        agg_kernel<<<((size_t)N * 64 + 255) / 256, 256, 0, stream>>>(
            xwb, csrA[br], offsA[br], cntA[br], dinvA[br], bA, listA[br], nlistA[br], N, hc);
        gemm_mfma_kernel<<<(N + 127) / 128, 256, 0, stream>>>(
            hc, WThi[2 + br], WTlo[2 + br], xw2c, N, nlistA[br], 128);
        root_agg_kernel<<<((size_t)R * 64 + 255) / 256, 256, 0, stream>>>(
            xw2c, invA[br], csrA[br], offsA[br], cntA[br], dinvA[br], bB, roots, R,
            feat, br * 128);
    }
    head_kernel<<<((size_t)R * 64 + 255) / 256, 256, 0, stream>>>(feat, fcw, fcb, out, R);
}